// Round 2
// baseline (675.285 us; speedup 1.0000x reference)
//
#include <hip/hip_runtime.h>
#include <hip/hip_bf16.h>
#include <cstdint>

typedef __attribute__((ext_vector_type(8))) __bf16 bf16x8;
typedef __attribute__((ext_vector_type(4))) float f32x4;
typedef unsigned int uint32;

#define LDS_AS __attribute__((address_space(3)))
#define GLB_AS __attribute__((address_space(1)))

static __device__ __forceinline__ void gld_lds16(const void* g, LDS_AS char* l) {
  __builtin_amdgcn_global_load_lds((const GLB_AS uint32*)g, (LDS_AS uint32*)l, 16, 0, 0);
}

#define MFMA(a, b, c) __builtin_amdgcn_mfma_f32_16x16x32_bf16((a), (b), (c), 0, 0, 0)

// 3-term split-bf16 MFMA: A*B ~= Ah*Bh + Al*Bh + Ah*Bl  (drop Al*Bl)
static __device__ __forceinline__ f32x4 mfma3(bf16x8 ah, bf16x8 al, bf16x8 bh,
                                              bf16x8 bl, f32x4 c) {
  c = MFMA(ah, bh, c);
  c = MFMA(al, bh, c);
  c = MFMA(ah, bl, c);
  return c;
}

static __device__ __forceinline__ void splitb(float x, __bf16& h, __bf16& l) {
  h = (__bf16)x;
  l = (__bf16)(x - (float)h);
}

// ---------------------------------------------------------------------------
// Attention, f32 in / f32 attn out / split-bf16 ctx out.
// Block = (head g, 64-row q block rb); 4 waves x 16 rows.
// Q = v_input, K = k_input, V = q_input (reference signature quirk).
// Two passes over 16 K-tiles: pass1 row max+sum (f32), pass2 P + PV.
// ---------------------------------------------------------------------------
__global__ __launch_bounds__(256) void attn_f32(
    const float* __restrict__ Kin, const float* __restrict__ Qin,
    const float* __restrict__ Vin, float* __restrict__ attn_out,
    __bf16* __restrict__ ctxH, __bf16* __restrict__ ctxL)
{
  __shared__ __attribute__((aligned(16))) __bf16 KsH[64][72], KsL[64][72];
  __shared__ __attribute__((aligned(16))) __bf16 VtH[64][72], VtL[64][72];
  __shared__ __attribute__((aligned(16))) __bf16 PsH[4][16][72], PsL[4][16][72];
  __shared__ __attribute__((aligned(16))) float PsF[4][16][64];

  const int tid = threadIdx.x;
  const int l = tid & 63, w = tid >> 6;
  const int lr = l & 15, lkb = (l >> 4) * 8;
  const int g = blockIdx.x >> 4, rb = blockIdx.x & 15;
  const size_t base = (size_t)g * 65536;

  // Q fragments in registers (per-lane row = w*16+lr), split hi/lo
  const float* qp = Qin + base + (size_t)(rb * 64 + w * 16 + lr) * 64;
  f32x4 q0a = *(const f32x4*)&qp[lkb];
  f32x4 q0b = *(const f32x4*)&qp[lkb + 4];
  f32x4 q1a = *(const f32x4*)&qp[32 + lkb];
  f32x4 q1b = *(const f32x4*)&qp[32 + lkb + 4];
  bf16x8 aqh0, aql0, aqh1, aql1;
#pragma unroll
  for (int j = 0; j < 4; ++j) {
    __bf16 h, lo;
    splitb(q0a[j], h, lo); aqh0[j] = h; aql0[j] = lo;
    splitb(q0b[j], h, lo); aqh0[4 + j] = h; aql0[4 + j] = lo;
    splitb(q1a[j], h, lo); aqh1[j] = h; aql1[j] = lo;
    splitb(q1b[j], h, lo); aqh1[4 + j] = h; aql1[4 + j] = lo;
  }

  float m_r[4], l_r[4];
#pragma unroll
  for (int r = 0; r < 4; ++r) { m_r[r] = -1e30f; l_r[r] = 0.f; }

  // ---- pass 1: stats ----
  for (int kt = 0; kt < 16; ++kt) {
    __syncthreads();
    for (int it = 0; it < 4; ++it) {
      int idx = it * 256 + tid, row = idx >> 4, cq = idx & 15;
      f32x4 kv = *(const f32x4*)&Kin[base + (size_t)(kt * 64 + row) * 64 + cq * 4];
#pragma unroll
      for (int j = 0; j < 4; ++j) {
        __bf16 h, lo;
        splitb(kv[j], h, lo);
        KsH[row][cq * 4 + j] = h;
        KsL[row][cq * 4 + j] = lo;
      }
    }
    __syncthreads();
#pragma unroll
    for (int nf = 0; nf < 4; ++nf) {
      f32x4 cc = {0.f, 0.f, 0.f, 0.f};
      cc = mfma3(aqh0, aql0, *(const bf16x8*)&KsH[nf * 16 + lr][lkb],
                 *(const bf16x8*)&KsL[nf * 16 + lr][lkb], cc);
      cc = mfma3(aqh1, aql1, *(const bf16x8*)&KsH[nf * 16 + lr][32 + lkb],
                 *(const bf16x8*)&KsL[nf * 16 + lr][32 + lkb], cc);
#pragma unroll
      for (int r = 0; r < 4; ++r) {
        // stash scaled scores per nf into cc reuse: handled below
        PsF[w][(l >> 4) * 4 + r][nf * 16 + lr] = cc[r] * 8.f;
      }
    }
    // per-row reduce using registers: reload own 4 scores per nf
#pragma unroll
    for (int r = 0; r < 4; ++r) {
      int prow = (l >> 4) * 4 + r;
      float s0 = PsF[w][prow][0 * 16 + lr], s1 = PsF[w][prow][1 * 16 + lr];
      float s2 = PsF[w][prow][2 * 16 + lr], s3 = PsF[w][prow][3 * 16 + lr];
      float tm = fmaxf(fmaxf(s0, s1), fmaxf(s2, s3));
#pragma unroll
      for (int o = 1; o < 16; o <<= 1) tm = fmaxf(tm, __shfl_xor(tm, o, 64));
      float mnew = fmaxf(m_r[r], tm);
      float se = __expf(s0 - mnew) + __expf(s1 - mnew) +
                 __expf(s2 - mnew) + __expf(s3 - mnew);
#pragma unroll
      for (int o = 1; o < 16; o <<= 1) se += __shfl_xor(se, o, 64);
      l_r[r] = l_r[r] * __expf(m_r[r] - mnew) + se;
      m_r[r] = mnew;
    }
  }
  float inv_l[4];
#pragma unroll
  for (int r = 0; r < 4; ++r) inv_l[r] = 1.f / l_r[r];

  f32x4 co[4];
#pragma unroll
  for (int cf = 0; cf < 4; ++cf) co[cf] = (f32x4){0.f, 0.f, 0.f, 0.f};

  // ---- pass 2: P write (f32 + split) + PV ----
  for (int kt = 0; kt < 16; ++kt) {
    __syncthreads();
    for (int it = 0; it < 4; ++it) {
      int idx = it * 256 + tid, row = idx >> 4, cq = idx & 15;
      size_t go = base + (size_t)(kt * 64 + row) * 64 + cq * 4;
      f32x4 kv = *(const f32x4*)&Kin[go];
      f32x4 vv = *(const f32x4*)&Vin[go];
#pragma unroll
      for (int j = 0; j < 4; ++j) {
        __bf16 h, lo;
        splitb(kv[j], h, lo);
        KsH[row][cq * 4 + j] = h;
        KsL[row][cq * 4 + j] = lo;
        splitb(vv[j], h, lo);
        VtH[cq * 4 + j][row] = h;
        VtL[cq * 4 + j][row] = lo;
      }
    }
    __syncthreads();
#pragma unroll
    for (int nf = 0; nf < 4; ++nf) {
      f32x4 cc = {0.f, 0.f, 0.f, 0.f};
      cc = mfma3(aqh0, aql0, *(const bf16x8*)&KsH[nf * 16 + lr][lkb],
                 *(const bf16x8*)&KsL[nf * 16 + lr][lkb], cc);
      cc = mfma3(aqh1, aql1, *(const bf16x8*)&KsH[nf * 16 + lr][32 + lkb],
                 *(const bf16x8*)&KsL[nf * 16 + lr][32 + lkb], cc);
#pragma unroll
      for (int r = 0; r < 4; ++r) {
        int prow = (l >> 4) * 4 + r;
        float p = __expf(cc[r] * 8.f - m_r[r]) * inv_l[r];
        PsF[w][prow][nf * 16 + lr] = p;
        __bf16 h, lo;
        splitb(p, h, lo);
        PsH[w][prow][nf * 16 + lr] = h;
        PsL[w][prow][nf * 16 + lr] = lo;
      }
    }
    // coalesced f32 attn store (wave's own 16x64 rows)
    for (int it2 = 0; it2 < 4; ++it2) {
      int slot = it2 * 64 + l, prow = slot >> 4, cq = slot & 15;
      f32x4 pd = *(const f32x4*)&PsF[w][prow][cq * 4];
      *(f32x4*)&attn_out[((size_t)(g * 1024 + rb * 64 + w * 16 + prow)) * 1024 +
                         kt * 64 + cq * 4] = pd;
    }
    bf16x8 ph0 = *(const bf16x8*)&PsH[w][lr][lkb];
    bf16x8 pl0 = *(const bf16x8*)&PsL[w][lr][lkb];
    bf16x8 ph1 = *(const bf16x8*)&PsH[w][lr][32 + lkb];
    bf16x8 pl1 = *(const bf16x8*)&PsL[w][lr][32 + lkb];
#pragma unroll
    for (int cf = 0; cf < 4; ++cf) {
      co[cf] = mfma3(ph0, pl0, *(const bf16x8*)&VtH[cf * 16 + lr][lkb],
                     *(const bf16x8*)&VtL[cf * 16 + lr][lkb], co[cf]);
      co[cf] = mfma3(ph1, pl1, *(const bf16x8*)&VtH[cf * 16 + lr][32 + lkb],
                     *(const bf16x8*)&VtL[cf * 16 + lr][32 + lkb], co[cf]);
    }
  }
#pragma unroll
  for (int cf = 0; cf < 4; ++cf)
#pragma unroll
    for (int r = 0; r < 4; ++r) {
      int i = w * 16 + (l >> 4) * 4 + r;
      size_t o = ((size_t)(g * 1024 + rb * 64 + i)) * 64 + cf * 16 + lr;
      __bf16 h, lo;
      splitb(co[cf][r], h, lo);
      ctxH[o] = h;
      ctxL[o] = lo;
    }
}

// ---------------------------------------------------------------------------
// Split-bf16 GEMM: C[MxN] = (AH+AL)[MxK] * ((BH+BL)[NxK])^T + bias (+Res)
// 128x128 tile, BK=64, 4 waves (2x2). EPI: 0/2 = +bias+Res -> f32 Out,
// 1 = relu(+bias) -> split bf16 OutH/OutL.
// ---------------------------------------------------------------------------
template <int EPI>
__global__ __launch_bounds__(256) void gemm_split(
    const __bf16* __restrict__ AH, const __bf16* __restrict__ AL,
    const __bf16* __restrict__ BH, const __bf16* __restrict__ BL,
    const float* __restrict__ bias, const float* __restrict__ Res,
    float* __restrict__ Out, __bf16* __restrict__ OutH,
    __bf16* __restrict__ OutL, int M, int N, int K)
{
  __shared__ __attribute__((aligned(16))) __bf16 sm[32768];  // AH|AL|BH|BL 16KB each
  const int tid = threadIdx.x;
  const int l = tid & 63, w = tid >> 6;
  const int lr = l & 15, lkb = (l >> 4) * 8;
  const int m0 = blockIdx.y * 128, n0 = blockIdx.x * 128;
  const int wr = (w >> 1) * 64, wc = (w & 1) * 64;
  LDS_AS char* sm3 = (LDS_AS char*)sm;

  f32x4 acc[4][4];
  f32x4 zero = {0.f, 0.f, 0.f, 0.f};
#pragma unroll
  for (int m = 0; m < 4; ++m)
#pragma unroll
    for (int n = 0; n < 4; ++n) acc[m][n] = zero;

  const int nkt = K >> 6;
  for (int kt = 0; kt < nkt; ++kt) {
    __syncthreads();
#pragma unroll
    for (int it = 0; it < 4; ++it) {
      int slot = it * 256 + tid;
      int row = slot >> 3, cb = slot & 7;
      size_t ga = (size_t)(m0 + row) * K + kt * 64 + cb * 8;
      size_t gb = (size_t)(n0 + row) * K + kt * 64 + cb * 8;
      gld_lds16(&AH[ga], sm3 + slot * 16);
      gld_lds16(&AL[ga], sm3 + 16384 + slot * 16);
      gld_lds16(&BH[gb], sm3 + 32768 + slot * 16);
      gld_lds16(&BL[gb], sm3 + 49152 + slot * 16);
    }
    __syncthreads();
#pragma unroll
    for (int kk = 0; kk < 2; ++kk) {
      bf16x8 ah[4], al[4], bh[4], bl[4];
#pragma unroll
      for (int m = 0; m < 4; ++m) {
        int off = (wr + m * 16 + lr) * 64 + kk * 32 + lkb;
        ah[m] = *(const bf16x8*)&sm[off];
        al[m] = *(const bf16x8*)&sm[8192 + off];
      }
#pragma unroll
      for (int n = 0; n < 4; ++n) {
        int off = (wc + n * 16 + lr) * 64 + kk * 32 + lkb;
        bh[n] = *(const bf16x8*)&sm[16384 + off];
        bl[n] = *(const bf16x8*)&sm[24576 + off];
      }
#pragma unroll
      for (int m = 0; m < 4; ++m)
#pragma unroll
        for (int n = 0; n < 4; ++n)
          acc[m][n] = mfma3(ah[m], al[m], bh[n], bl[n], acc[m][n]);
    }
  }

#pragma unroll
  for (int n = 0; n < 4; ++n) {
    int gcol = n0 + wc + n * 16 + lr;
    float bc = bias[gcol];
#pragma unroll
    for (int m = 0; m < 4; ++m) {
      int grow = m0 + wr + m * 16 + (l >> 4) * 4;
#pragma unroll
      for (int r = 0; r < 4; ++r) {
        float v = acc[m][n][r] + bc;
        size_t o = (size_t)(grow + r) * N + gcol;
        if (EPI == 1) {
          v = fmaxf(v, 0.f);
          __bf16 h, lo;
          splitb(v, h, lo);
          OutH[o] = h;
          OutL[o] = lo;
        } else {
          v += Res[o];
          Out[o] = v;
        }
      }
    }
  }
}

// ---------------------------------------------------------------------------
// 32x32 transpose + split: f32 in[R x C] -> bf16 hi/lo out[C x R]
// ---------------------------------------------------------------------------
__global__ __launch_bounds__(256) void transpose_split(
    const float* __restrict__ in, __bf16* __restrict__ outH,
    __bf16* __restrict__ outL, int R, int C)
{
  __shared__ float tile[32][33];
  int bx = blockIdx.x * 32, by = blockIdx.y * 32;
  int tx = threadIdx.x & 31, ty = threadIdx.x >> 5;
  for (int i = ty; i < 32; i += 8)
    tile[i][tx] = in[(size_t)(by + i) * C + bx + tx];
  __syncthreads();
  for (int i = ty; i < 32; i += 8) {
    __bf16 h, lo;
    splitb(tile[tx][i], h, lo);
    size_t o = (size_t)(bx + i) * R + by + tx;
    outH[o] = h;
    outL[o] = lo;
  }
}

// ---------------------------------------------------------------------------
// LayerNorm over D=1024, one block per row; optional split-bf16 side output.
// ---------------------------------------------------------------------------
template <int SPLIT>
__global__ __launch_bounds__(256) void ln_split(
    const float* __restrict__ in, const float* __restrict__ gam,
    const float* __restrict__ bet, float* __restrict__ out,
    __bf16* __restrict__ outH, __bf16* __restrict__ outL)
{
  __shared__ float red[8];
  const int row = blockIdx.x, t = threadIdx.x;
  const float* rp = in + (size_t)row * 1024;
  f32x4 v = ((const f32x4*)rp)[t];
  float s = 0.f, ss = 0.f;
#pragma unroll
  for (int j = 0; j < 4; ++j) {
    s += v[j];
    ss += v[j] * v[j];
  }
#pragma unroll
  for (int o = 1; o < 64; o <<= 1) {
    s += __shfl_xor(s, o, 64);
    ss += __shfl_xor(ss, o, 64);
  }
  int w = t >> 6, l = t & 63;
  if (l == 0) { red[w] = s; red[4 + w] = ss; }
  __syncthreads();
  float S = red[0] + red[1] + red[2] + red[3];
  float SS = red[4] + red[5] + red[6] + red[7];
  float mean = S * (1.f / 1024.f);
  float var = SS * (1.f / 1024.f) - mean * mean;
  float rstd = rsqrtf(var + 1e-5f);
  f32x4 ov;
#pragma unroll
  for (int j = 0; j < 4; ++j) {
    int col = t * 4 + j;
    ov[j] = (v[j] - mean) * rstd * gam[col] + bet[col];
  }
  ((f32x4*)(out + (size_t)row * 1024))[t] = ov;
  if (SPLIT) {
#pragma unroll
    for (int j = 0; j < 4; ++j) {
      __bf16 h, lo;
      splitb(ov[j], h, lo);
      size_t o = (size_t)row * 1024 + t * 4 + j;
      outH[o] = h;
      outL[o] = lo;
    }
  }
}

// ---------------------------------------------------------------------------
extern "C" void kernel_launch(void* const* d_in, const int* in_sizes, int n_in,
                              void* d_out, int out_size, void* d_ws, size_t ws_size,
                              hipStream_t stream) {
  const float* k_in = (const float*)d_in[0];
  const float* v_in = (const float*)d_in[1];
  const float* q_in = (const float*)d_in[2];
  const float* r_in = (const float*)d_in[3];
  const float* Wf = (const float*)d_in[4];
  const float* bf = (const float*)d_in[5];
  const float* g1 = (const float*)d_in[6];
  const float* b1 = (const float*)d_in[7];
  const float* W1 = (const float*)d_in[8];
  const float* bw1 = (const float*)d_in[9];
  const float* W2 = (const float*)d_in[10];
  const float* bw2 = (const float*)d_in[11];
  const float* g2 = (const float*)d_in[12];
  const float* b2 = (const float*)d_in[13];

  float* out0 = (float*)d_out;          // [4096,1024]
  float* attn = out0 + 4194304;         // [64,1024,1024]

  char* W = (char*)d_ws;
  const size_t MB = 1024 * 1024;
  __bf16* WFTH = (__bf16*)(W + 0);
  __bf16* WFTL = (__bf16*)(W + 2 * MB);
  __bf16* W1TH = (__bf16*)(W + 4 * MB);
  __bf16* W1TL = (__bf16*)(W + 12 * MB);
  __bf16* W2TH = (__bf16*)(W + 20 * MB);
  __bf16* W2TL = (__bf16*)(W + 28 * MB);
  __bf16* CTXH = (__bf16*)(W + 36 * MB);
  __bf16* CTXL = (__bf16*)(W + 44 * MB);
  float* T1 = (float*)(W + 52 * MB);    // 16MB, reused as T2
  float* X = (float*)(W + 68 * MB);     // 16MB
  __bf16* XH = (__bf16*)(W + 84 * MB);
  __bf16* XL = (__bf16*)(W + 92 * MB);
  __bf16* HH = (__bf16*)(W + 100 * MB); // 32MB
  __bf16* HL = (__bf16*)(W + 132 * MB); // 32MB
  float* T2 = T1;

  transpose_split<<<dim3(32, 32), 256, 0, stream>>>(Wf, WFTH, WFTL, 1024, 1024);
  transpose_split<<<dim3(128, 32), 256, 0, stream>>>(W1, W1TH, W1TL, 1024, 4096);
  transpose_split<<<dim3(32, 128), 256, 0, stream>>>(W2, W2TH, W2TL, 4096, 1024);

  attn_f32<<<1024, 256, 0, stream>>>(k_in, v_in, q_in, attn, CTXH, CTXL);

  // t1 = r + ctx @ Wf + bf
  gemm_split<0><<<dim3(8, 32), 256, 0, stream>>>(CTXH, CTXL, WFTH, WFTL, bf, r_in,
                                                 T1, nullptr, nullptr, 4096, 1024, 1024);
  ln_split<1><<<4096, 256, 0, stream>>>(T1, g1, b1, X, XH, XL);
  // h = relu(x @ W1 + bw1) -> split
  gemm_split<1><<<dim3(32, 32), 256, 0, stream>>>(XH, XL, W1TH, W1TL, bw1, nullptr,
                                                  nullptr, HH, HL, 4096, 4096, 1024);
  // t2 = x + h @ W2 + bw2
  gemm_split<2><<<dim3(8, 32), 256, 0, stream>>>(HH, HL, W2TH, W2TL, bw2, X,
                                                 T2, nullptr, nullptr, 4096, 1024, 4096);
  ln_split<0><<<4096, 256, 0, stream>>>(T2, g2, b2, out0, nullptr, nullptr);
}

// Round 3
// 398.439 us; speedup vs baseline: 1.6948x; 1.6948x over previous
//
#include <hip/hip_runtime.h>
#include <hip/hip_bf16.h>
#include <cstdint>

typedef __attribute__((ext_vector_type(8))) __bf16 bf16x8;
typedef __attribute__((ext_vector_type(4))) __bf16 bf16x4;
typedef __attribute__((ext_vector_type(4))) float f32x4;
typedef unsigned int uint32;
typedef unsigned short uint16;

#define LDS_AS __attribute__((address_space(3)))
#define GLB_AS __attribute__((address_space(1)))

static __device__ __forceinline__ void gld_lds16(const void* g, LDS_AS char* l) {
  __builtin_amdgcn_global_load_lds((const GLB_AS uint32*)g, (LDS_AS uint32*)l, 16, 0, 0);
}

#define MFMA(a, b, c) __builtin_amdgcn_mfma_f32_16x16x32_bf16((a), (b), (c), 0, 0, 0)

// 3-term split-bf16 MFMA: A*B ~= Ah*Bh + Al*Bh + Ah*Bl
static __device__ __forceinline__ f32x4 mfma3(bf16x8 ah, bf16x8 al, bf16x8 bh,
                                              bf16x8 bl, f32x4 c) {
  c = MFMA(ah, bh, c);
  c = MFMA(al, bh, c);
  c = MFMA(ah, bl, c);
  return c;
}

static __device__ __forceinline__ uint32 pack_bf16(float a, float b) {
  __bf16 ha = (__bf16)a, hb = (__bf16)b;
  return (uint32)__builtin_bit_cast(uint16, ha) |
         ((uint32)__builtin_bit_cast(uint16, hb) << 16);
}

// ---------------------------------------------------------------------------
// Attention v3: block = (head g, 128-row q block rb), 8 waves x 16 q rows.
// Q = v_input, K = k_input, V = q_input (reference signature quirk).
// Split-bf16 QK^T (accuracy-critical); plain bf16 P.V.
// Pass 1: stats (m,l) per row. Pass 2: P write (f32 attn + bf16 Ps) + PV.
// ---------------------------------------------------------------------------
__global__ __launch_bounds__(512, 4) void attn_v3(
    const float* __restrict__ Kin, const float* __restrict__ Qin,
    const float* __restrict__ Vin, float* __restrict__ attn_out,
    __bf16* __restrict__ ctx_out)
{
  __shared__ __attribute__((aligned(16))) __bf16 KsH[64][72];
  __shared__ __attribute__((aligned(16))) __bf16 KsL[64][72];
  __shared__ __attribute__((aligned(16))) uint32 Vt32[64][36];  // V^T, k-pairs packed
  __shared__ __attribute__((aligned(16))) __bf16 PsH[8][16][72];

  const int tid = threadIdx.x;
  const int l = tid & 63, w = tid >> 6;
  const int lr = l & 15, q4 = l >> 4;
  const int lkb = q4 * 8;
  const int g = blockIdx.x >> 3, rb = blockIdx.x & 7;
  const size_t base = (size_t)g * 65536;

  // Q fragments in registers (per-lane row = rb*128 + w*16 + lr), split hi/lo
  const float* qp = Qin + base + (size_t)(rb * 128 + w * 16 + lr) * 64;
  bf16x8 aqh0, aql0, aqh1, aql1;
#pragma unroll
  for (int j = 0; j < 8; ++j) {
    float x0 = qp[lkb + (j & 3) + (j >> 2) * 4];
    float x1 = qp[32 + lkb + (j & 3) + (j >> 2) * 4];
    __bf16 h0 = (__bf16)x0, h1 = (__bf16)x1;
    aqh0[j] = h0; aql0[j] = (__bf16)(x0 - (float)h0);
    aqh1[j] = h1; aql1[j] = (__bf16)(x1 - (float)h1);
  }

  float m_r[4], l_r[4];
#pragma unroll
  for (int r = 0; r < 4; ++r) { m_r[r] = -1e30f; l_r[r] = 0.f; }

  // ---- pass 1: stats ----
  for (int kt = 0; kt < 16; ++kt) {
    __syncthreads();
#pragma unroll
    for (int it = 0; it < 2; ++it) {
      int idx = it * 512 + tid, row = idx >> 4, cq = idx & 15;
      f32x4 kv = *(const f32x4*)&Kin[base + (size_t)(kt * 64 + row) * 64 + cq * 4];
      bf16x4 h, lo;
#pragma unroll
      for (int j = 0; j < 4; ++j) {
        h[j] = (__bf16)kv[j];
        lo[j] = (__bf16)(kv[j] - (float)h[j]);
      }
      *(bf16x4*)&KsH[row][cq * 4] = h;
      *(bf16x4*)&KsL[row][cq * 4] = lo;
    }
    __syncthreads();
    f32x4 c[4];
#pragma unroll
    for (int nf = 0; nf < 4; ++nf) {
      f32x4 cc = {0.f, 0.f, 0.f, 0.f};
      cc = mfma3(aqh0, aql0, *(const bf16x8*)&KsH[nf * 16 + lr][lkb],
                 *(const bf16x8*)&KsL[nf * 16 + lr][lkb], cc);
      cc = mfma3(aqh1, aql1, *(const bf16x8*)&KsH[nf * 16 + lr][32 + lkb],
                 *(const bf16x8*)&KsL[nf * 16 + lr][32 + lkb], cc);
      c[nf] = cc;
    }
#pragma unroll
    for (int r = 0; r < 4; ++r) {
      float s0 = c[0][r] * 8.f, s1 = c[1][r] * 8.f;
      float s2 = c[2][r] * 8.f, s3 = c[3][r] * 8.f;
      float tm = fmaxf(fmaxf(s0, s1), fmaxf(s2, s3));
#pragma unroll
      for (int o = 1; o < 16; o <<= 1) tm = fmaxf(tm, __shfl_xor(tm, o, 64));
      float mnew = fmaxf(m_r[r], tm);
      float se = __expf(s0 - mnew) + __expf(s1 - mnew) +
                 __expf(s2 - mnew) + __expf(s3 - mnew);
#pragma unroll
      for (int o = 1; o < 16; o <<= 1) se += __shfl_xor(se, o, 64);
      l_r[r] = l_r[r] * __expf(m_r[r] - mnew) + se;
      m_r[r] = mnew;
    }
  }
  float inv_l[4];
#pragma unroll
  for (int r = 0; r < 4; ++r) inv_l[r] = 1.f / l_r[r];

  f32x4 co[4];
#pragma unroll
  for (int cf = 0; cf < 4; ++cf) co[cf] = (f32x4){0.f, 0.f, 0.f, 0.f};

  // ---- pass 2: P (f32 attn out + bf16 Ps) + PV ----
  for (int kt = 0; kt < 16; ++kt) {
    __syncthreads();
#pragma unroll
    for (int it = 0; it < 2; ++it) {
      int idx = it * 512 + tid, row = idx >> 4, cq = idx & 15;
      f32x4 kv = *(const f32x4*)&Kin[base + (size_t)(kt * 64 + row) * 64 + cq * 4];
      bf16x4 h, lo;
#pragma unroll
      for (int j = 0; j < 4; ++j) {
        h[j] = (__bf16)kv[j];
        lo[j] = (__bf16)(kv[j] - (float)h[j]);
      }
      *(bf16x4*)&KsH[row][cq * 4] = h;
      *(bf16x4*)&KsL[row][cq * 4] = lo;
    }
    {
      int kp = tid >> 4, cq = tid & 15;
      const float* vr = Vin + base + (size_t)(kt * 64 + 2 * kp) * 64 + cq * 4;
      f32x4 va = *(const f32x4*)vr;
      f32x4 vb = *(const f32x4*)(vr + 64);
#pragma unroll
      for (int j = 0; j < 4; ++j)
        Vt32[cq * 4 + j][kp] = pack_bf16(va[j], vb[j]);
    }
    __syncthreads();
#pragma unroll
    for (int nf = 0; nf < 4; ++nf) {
      f32x4 cc = {0.f, 0.f, 0.f, 0.f};
      cc = mfma3(aqh0, aql0, *(const bf16x8*)&KsH[nf * 16 + lr][lkb],
                 *(const bf16x8*)&KsL[nf * 16 + lr][lkb], cc);
      cc = mfma3(aqh1, aql1, *(const bf16x8*)&KsH[nf * 16 + lr][32 + lkb],
                 *(const bf16x8*)&KsL[nf * 16 + lr][32 + lkb], cc);
#pragma unroll
      for (int r = 0; r < 4; ++r) {
        float p = __expf(cc[r] * 8.f - m_r[r]) * inv_l[r];
        PsH[w][q4 * 4 + r][nf * 16 + lr] = (__bf16)p;
        int arow = rb * 128 + w * 16 + q4 * 4 + r;
        attn_out[((size_t)(g * 1024 + arow)) * 1024 + kt * 64 + nf * 16 + lr] = p;
      }
    }
    // PV: same-wave LDS dependency (PsH[w]) — no barrier needed
#pragma unroll
    for (int kk = 0; kk < 2; ++kk) {
      bf16x8 ph = *(const bf16x8*)&PsH[w][lr][kk * 32 + lkb];
#pragma unroll
      for (int cf = 0; cf < 4; ++cf) {
        bf16x8 vt = *(const bf16x8*)&Vt32[cf * 16 + lr][kk * 16 + q4 * 4];
        co[cf] = MFMA(ph, vt, co[cf]);
      }
    }
  }
#pragma unroll
  for (int cf = 0; cf < 4; ++cf)
#pragma unroll
    for (int r = 0; r < 4; ++r) {
      int i = rb * 128 + w * 16 + q4 * 4 + r;
      ctx_out[((size_t)(g * 1024 + i)) * 64 + cf * 16 + lr] = (__bf16)co[cf][r];
    }
}

// ---------------------------------------------------------------------------
// m97-structure bf16 GEMM: C = A[MxK] * Bt[NxK]^T + bias (+Res).
// EPI 0: Outf = acc + bias + Res (f32).  EPI 1: Outb = bf16(relu(acc+bias)).
// ---------------------------------------------------------------------------
template <int EPI>
__global__ __launch_bounds__(256) void gemm_bt(
    const __bf16* __restrict__ A, const __bf16* __restrict__ Bt,
    const float* __restrict__ bias, const float* __restrict__ Res,
    float* __restrict__ Outf, __bf16* __restrict__ Outb, int M, int N, int K)
{
  __shared__ __attribute__((aligned(16))) __bf16 sm[16384];
  const int tid = threadIdx.x;
  const int l = tid & 63, w = tid >> 6;
  const int lr = l & 15, lkb = (l >> 4) * 8;
  const int m0 = blockIdx.y * 128, n0 = blockIdx.x * 128;
  const int wr = (w >> 1) * 64, wc = (w & 1) * 64;
  LDS_AS char* sm3 = (LDS_AS char*)sm;

  f32x4 acc[4][4];
  f32x4 zero = {0.f, 0.f, 0.f, 0.f};
#pragma unroll
  for (int m = 0; m < 4; ++m)
#pragma unroll
    for (int n = 0; n < 4; ++n) acc[m][n] = zero;

  const int nkt = K >> 6;
  for (int kt = 0; kt < nkt; ++kt) {
    __syncthreads();
#pragma unroll
    for (int it = 0; it < 4; ++it) {
      int slot = it * 256 + tid;
      int row = slot >> 3, cb = slot & 7;
      gld_lds16(&A[(size_t)(m0 + row) * K + kt * 64 + cb * 8], sm3 + slot * 16);
      gld_lds16(&Bt[(size_t)(n0 + row) * K + kt * 64 + cb * 8],
                sm3 + 16384 + slot * 16);
    }
    __syncthreads();
#pragma unroll
    for (int kk = 0; kk < 2; ++kk) {
      bf16x8 a[4], b[4];
#pragma unroll
      for (int m = 0; m < 4; ++m)
        a[m] = *(const bf16x8*)&sm[(wr + m * 16 + lr) * 64 + kk * 32 + lkb];
#pragma unroll
      for (int n = 0; n < 4; ++n)
        b[n] = *(const bf16x8*)&sm[8192 + (wc + n * 16 + lr) * 64 + kk * 32 + lkb];
#pragma unroll
      for (int m = 0; m < 4; ++m)
#pragma unroll
        for (int n = 0; n < 4; ++n) acc[m][n] = MFMA(a[m], b[n], acc[m][n]);
    }
  }

#pragma unroll
  for (int n = 0; n < 4; ++n) {
    int gcol = n0 + wc + n * 16 + lr;
    float bc = bias[gcol];
#pragma unroll
    for (int m = 0; m < 4; ++m) {
      int grow = m0 + wr + m * 16 + (l >> 4) * 4;
#pragma unroll
      for (int r = 0; r < 4; ++r) {
        float v = acc[m][n][r] + bc;
        size_t o = (size_t)(grow + r) * N + gcol;
        if (EPI == 1) {
          Outb[o] = (__bf16)fmaxf(v, 0.f);
        } else {
          Outf[o] = v + Res[o];
        }
      }
    }
  }
}

// ---------------------------------------------------------------------------
// 32x32 transpose, f32 in -> bf16 out: out[C x R] = bf16(in[R x C]^T)
// ---------------------------------------------------------------------------
__global__ __launch_bounds__(256) void transpose_f32_bf16(
    const float* __restrict__ in, __bf16* __restrict__ out, int R, int C)
{
  __shared__ float tile[32][33];
  int bx = blockIdx.x * 32, by = blockIdx.y * 32;
  int tx = threadIdx.x & 31, ty = threadIdx.x >> 5;
  for (int i = ty; i < 32; i += 8)
    tile[i][tx] = in[(size_t)(by + i) * C + bx + tx];
  __syncthreads();
  for (int i = ty; i < 32; i += 8)
    out[(size_t)(bx + i) * R + by + tx] = (__bf16)tile[tx][i];
}

// ---------------------------------------------------------------------------
// LayerNorm over D=1024, one block per row; optional bf16 side output.
// ---------------------------------------------------------------------------
template <int SPLIT>
__global__ __launch_bounds__(256) void ln_split(
    const float* __restrict__ in, const float* __restrict__ gam,
    const float* __restrict__ bet, float* __restrict__ out,
    __bf16* __restrict__ outB)
{
  __shared__ float red[8];
  const int row = blockIdx.x, t = threadIdx.x;
  const float* rp = in + (size_t)row * 1024;
  f32x4 v = ((const f32x4*)rp)[t];
  float s = 0.f, ss = 0.f;
#pragma unroll
  for (int j = 0; j < 4; ++j) {
    s += v[j];
    ss += v[j] * v[j];
  }
#pragma unroll
  for (int o = 1; o < 64; o <<= 1) {
    s += __shfl_xor(s, o, 64);
    ss += __shfl_xor(ss, o, 64);
  }
  int w = t >> 6, l = t & 63;
  if (l == 0) { red[w] = s; red[4 + w] = ss; }
  __syncthreads();
  float S = red[0] + red[1] + red[2] + red[3];
  float SS = red[4] + red[5] + red[6] + red[7];
  float mean = S * (1.f / 1024.f);
  float var = SS * (1.f / 1024.f) - mean * mean;
  float rstd = rsqrtf(var + 1e-5f);
  f32x4 ov;
#pragma unroll
  for (int j = 0; j < 4; ++j) {
    int col = t * 4 + j;
    ov[j] = (v[j] - mean) * rstd * gam[col] + bet[col];
  }
  ((f32x4*)(out + (size_t)row * 1024))[t] = ov;
  if (SPLIT) {
    bf16x4 ob;
#pragma unroll
    for (int j = 0; j < 4; ++j) ob[j] = (__bf16)ov[j];
    *(bf16x4*)&outB[(size_t)row * 1024 + t * 4] = ob;
  }
}

// ---------------------------------------------------------------------------
extern "C" void kernel_launch(void* const* d_in, const int* in_sizes, int n_in,
                              void* d_out, int out_size, void* d_ws, size_t ws_size,
                              hipStream_t stream) {
  const float* k_in = (const float*)d_in[0];
  const float* v_in = (const float*)d_in[1];
  const float* q_in = (const float*)d_in[2];
  const float* r_in = (const float*)d_in[3];
  const float* Wf = (const float*)d_in[4];
  const float* bf = (const float*)d_in[5];
  const float* g1 = (const float*)d_in[6];
  const float* b1 = (const float*)d_in[7];
  const float* W1 = (const float*)d_in[8];
  const float* bw1 = (const float*)d_in[9];
  const float* W2 = (const float*)d_in[10];
  const float* bw2 = (const float*)d_in[11];
  const float* g2 = (const float*)d_in[12];
  const float* b2 = (const float*)d_in[13];

  float* out0 = (float*)d_out;          // [4096,1024]
  float* attn = out0 + 4194304;         // [64,1024,1024]

  char* W = (char*)d_ws;
  const size_t MB = 1024 * 1024;
  __bf16* WFT = (__bf16*)(W + 0);        // 2MB  [1024][1024]
  __bf16* W1T = (__bf16*)(W + 2 * MB);   // 8MB  [4096][1024]
  __bf16* W2T = (__bf16*)(W + 10 * MB);  // 8MB  [1024][4096]
  __bf16* CTX = (__bf16*)(W + 18 * MB);  // 8MB  [4096][1024]
  __bf16* Xb = (__bf16*)(W + 26 * MB);   // 8MB
  __bf16* Hb = (__bf16*)(W + 34 * MB);   // 32MB [4096][4096]
  float* T1 = (float*)(W + 66 * MB);     // 16MB (reused as T2)
  float* X = (float*)(W + 82 * MB);      // 16MB
  float* T2 = T1;

  transpose_f32_bf16<<<dim3(32, 32), 256, 0, stream>>>(Wf, WFT, 1024, 1024);
  transpose_f32_bf16<<<dim3(128, 32), 256, 0, stream>>>(W1, W1T, 1024, 4096);
  transpose_f32_bf16<<<dim3(32, 128), 256, 0, stream>>>(W2, W2T, 4096, 1024);

  attn_v3<<<512, 512, 0, stream>>>(k_in, v_in, q_in, attn, CTX);

  // t1 = r + ctx @ Wf + bf
  gemm_bt<0><<<dim3(8, 32), 256, 0, stream>>>(CTX, WFT, bf, r_in, T1, nullptr,
                                              4096, 1024, 1024);
  ln_split<1><<<4096, 256, 0, stream>>>(T1, g1, b1, X, Xb);
  // h = relu(x @ W1 + bw1) -> bf16
  gemm_bt<1><<<dim3(32, 32), 256, 0, stream>>>(Xb, W1T, bw1, nullptr, nullptr, Hb,
                                               4096, 4096, 1024);
  // t2 = x + h @ W2 + bw2
  gemm_bt<0><<<dim3(8, 32), 256, 0, stream>>>(Hb, W2T, bw2, X, T2, nullptr,
                                              4096, 1024, 4096);
  ln_split<0><<<4096, 256, 0, stream>>>(T2, g2, b2, out0, nullptr);
}

// Round 4
// 366.279 us; speedup vs baseline: 1.8436x; 1.0878x over previous
//
#include <hip/hip_runtime.h>
#include <hip/hip_bf16.h>
#include <cstdint>

typedef __attribute__((ext_vector_type(8))) __bf16 bf16x8;
typedef __attribute__((ext_vector_type(4))) __bf16 bf16x4;
typedef __attribute__((ext_vector_type(4))) float f32x4;
typedef unsigned int uint32;
typedef unsigned short uint16;

#define LDS_AS __attribute__((address_space(3)))
#define GLB_AS __attribute__((address_space(1)))

static __device__ __forceinline__ void gld_lds16(const void* g, LDS_AS char* l) {
  __builtin_amdgcn_global_load_lds((const GLB_AS uint32*)g, (LDS_AS uint32*)l, 16, 0, 0);
}

#define MFMA(a, b, c) __builtin_amdgcn_mfma_f32_16x16x32_bf16((a), (b), (c), 0, 0, 0)

// 3-term split-bf16 MFMA: A*B ~= Ah*Bh + Al*Bh + Ah*Bl
static __device__ __forceinline__ f32x4 mfma3(bf16x8 ah, bf16x8 al, bf16x8 bh,
                                              bf16x8 bl, f32x4 c) {
  c = MFMA(ah, bh, c);
  c = MFMA(al, bh, c);
  c = MFMA(ah, bl, c);
  return c;
}

static __device__ __forceinline__ uint32 pack_bf16(float a, float b) {
  __bf16 ha = (__bf16)a, hb = (__bf16)b;
  return (uint32)__builtin_bit_cast(uint16, ha) |
         ((uint32)__builtin_bit_cast(uint16, hb) << 16);
}

// XOR swizzle: spreads stride-128B rows across banks (T2, rule #21 both-sides)
#define KB(row, colbyte) ((((row) * 128 + (colbyte))) ^ (((row) & 7) << 4))

// ---------------------------------------------------------------------------
// prep_k: K f32 [64 heads][1024][64] -> per-(head,tile) swizzled LDS images of
// split bf16 hi/lo: KH/KL[(h*16+kt)*8192 bytes], element (r,c) at KB(r, c*2).
// ---------------------------------------------------------------------------
__global__ __launch_bounds__(256) void prep_k(const float* __restrict__ K,
                                              char* __restrict__ KH,
                                              char* __restrict__ KL) {
  int kt = blockIdx.x & 15, h = blockIdx.x >> 4;
  const float* src = K + (size_t)h * 65536 + kt * 4096;
  char* dh = KH + (size_t)(h * 16 + kt) * 8192;
  char* dl = KL + (size_t)(h * 16 + kt) * 8192;
  int r = threadIdx.x >> 2, cq = threadIdx.x & 3;
  const float* sp = src + r * 64 + cq * 16;
  bf16x8 h0, l0, h1, l1;
#pragma unroll
  for (int j = 0; j < 8; ++j) {
    float x0 = sp[j], x1 = sp[8 + j];
    __bf16 a = (__bf16)x0, b = (__bf16)x1;
    h0[j] = a; l0[j] = (__bf16)(x0 - (float)a);
    h1[j] = b; l1[j] = (__bf16)(x1 - (float)b);
  }
  int sw = (r & 7) << 4;
  int o0 = (r * 128 + cq * 32) ^ sw;
  int o1 = (r * 128 + cq * 32 + 16) ^ sw;
  *(bf16x8*)(dh + o0) = h0;
  *(bf16x8*)(dh + o1) = h1;
  *(bf16x8*)(dl + o0) = l0;
  *(bf16x8*)(dl + o1) = l1;
}

// ---------------------------------------------------------------------------
// prep_v: V f32 -> per-(head,tile) swizzled V^T image, k-pairs packed as u32.
// u32 (d, kp) = pack(V[2kp][d], V[2kp+1][d]) stored at KB(d, kp*4).
// ---------------------------------------------------------------------------
__global__ __launch_bounds__(256) void prep_v(const float* __restrict__ V,
                                              char* __restrict__ VT) {
  int kt = blockIdx.x & 15, h = blockIdx.x >> 4;
  const float* src = V + (size_t)h * 65536 + kt * 4096;
  char* dv = VT + (size_t)(h * 16 + kt) * 8192;
  int kp = threadIdx.x >> 3, dq = threadIdx.x & 7;
  const float* s0 = src + (2 * kp) * 64 + dq * 8;
  const float* s1 = s0 + 64;
#pragma unroll
  for (int j = 0; j < 8; ++j) {
    uint32 pk = pack_bf16(s0[j], s1[j]);
    int d = dq * 8 + j;
    *(uint32*)(dv + ((d * 128 + kp * 4) ^ ((d & 7) << 4))) = pk;
  }
}

// ---------------------------------------------------------------------------
// Attention v4: block = (head g, 128-row q block rb), 8 waves x 16 q rows.
// Q = v_input, K = k_input, V = q_input (reference signature quirk).
// K/V staged via global_load_lds from prepped swizzled images (zero VALU).
// Split-bf16 QK^T; plain bf16 P.V. XCD-swizzled bid: head resident in one L2.
// ---------------------------------------------------------------------------
__global__ __launch_bounds__(512, 4) void attn_v4(
    const float* __restrict__ Qin, const char* __restrict__ KHimg,
    const char* __restrict__ KLimg, const char* __restrict__ VTimg,
    float* __restrict__ attn_out, __bf16* __restrict__ ctx_out)
{
  __shared__ __attribute__((aligned(16))) char KsH[8192];
  __shared__ __attribute__((aligned(16))) char KsL[8192];
  __shared__ __attribute__((aligned(16))) char Vt[8192];
  __shared__ __attribute__((aligned(16))) __bf16 PsH[8][16][72];

  const int tid = threadIdx.x;
  const int l = tid & 63, w = tid >> 6;
  const int lr = l & 15, q4 = l >> 4;
  const int swz = (blockIdx.x & 7) * 64 + (blockIdx.x >> 3);  // XCD chunking
  const int g = swz >> 3, rb = swz & 7;
  const size_t base = (size_t)g * 65536;
  const char* khb = KHimg + (size_t)g * 131072;
  const char* klb = KLimg + (size_t)g * 131072;
  const char* vtb = VTimg + (size_t)g * 131072;
  LDS_AS char* KsH3 = (LDS_AS char*)KsH;
  LDS_AS char* KsL3 = (LDS_AS char*)KsL;
  LDS_AS char* Vt3 = (LDS_AS char*)Vt;

  // Q fragments (per-lane row = rb*128 + w*16 + lr), split hi/lo
  const float* qp = Qin + base + (size_t)(rb * 128 + w * 16 + lr) * 64;
  bf16x8 aqh0, aql0, aqh1, aql1;
#pragma unroll
  for (int j = 0; j < 8; ++j) {
    float x0 = qp[q4 * 8 + j];
    float x1 = qp[32 + q4 * 8 + j];
    __bf16 h0 = (__bf16)x0, h1 = (__bf16)x1;
    aqh0[j] = h0; aql0[j] = (__bf16)(x0 - (float)h0);
    aqh1[j] = h1; aql1[j] = (__bf16)(x1 - (float)h1);
  }

  float m_r[4], l_r[4];
#pragma unroll
  for (int r = 0; r < 4; ++r) { m_r[r] = -1e30f; l_r[r] = 0.f; }

  // ---- pass 1: stats ----
  for (int kt = 0; kt < 16; ++kt) {
    __syncthreads();
    gld_lds16(khb + kt * 8192 + tid * 16, KsH3 + tid * 16);
    gld_lds16(klb + kt * 8192 + tid * 16, KsL3 + tid * 16);
    __syncthreads();
    f32x4 c[4];
#pragma unroll
    for (int nf = 0; nf < 4; ++nf) {
      int row = nf * 16 + lr;
      f32x4 cc = {0.f, 0.f, 0.f, 0.f};
      cc = mfma3(aqh0, aql0, *(const bf16x8*)(KsH + KB(row, q4 * 16)),
                 *(const bf16x8*)(KsL + KB(row, q4 * 16)), cc);
      cc = mfma3(aqh1, aql1, *(const bf16x8*)(KsH + KB(row, 64 + q4 * 16)),
                 *(const bf16x8*)(KsL + KB(row, 64 + q4 * 16)), cc);
      c[nf] = cc;
    }
#pragma unroll
    for (int r = 0; r < 4; ++r) {
      float s0 = c[0][r] * 8.f, s1 = c[1][r] * 8.f;
      float s2 = c[2][r] * 8.f, s3 = c[3][r] * 8.f;
      float tm = fmaxf(fmaxf(s0, s1), fmaxf(s2, s3));
#pragma unroll
      for (int o = 1; o < 16; o <<= 1) tm = fmaxf(tm, __shfl_xor(tm, o, 64));
      float mnew = fmaxf(m_r[r], tm);
      float se = __expf(s0 - mnew) + __expf(s1 - mnew) +
                 __expf(s2 - mnew) + __expf(s3 - mnew);
#pragma unroll
      for (int o = 1; o < 16; o <<= 1) se += __shfl_xor(se, o, 64);
      l_r[r] = l_r[r] * __expf(m_r[r] - mnew) + se;
      m_r[r] = mnew;
    }
  }
  float inv_l[4];
#pragma unroll
  for (int r = 0; r < 4; ++r) inv_l[r] = 1.f / l_r[r];

  f32x4 co[4];
#pragma unroll
  for (int cf = 0; cf < 4; ++cf) co[cf] = (f32x4){0.f, 0.f, 0.f, 0.f};

  // ---- pass 2: P (f32 attn out + bf16 Ps) + PV ----
  for (int kt = 0; kt < 16; ++kt) {
    __syncthreads();
    gld_lds16(khb + kt * 8192 + tid * 16, KsH3 + tid * 16);
    gld_lds16(klb + kt * 8192 + tid * 16, KsL3 + tid * 16);
    gld_lds16(vtb + kt * 8192 + tid * 16, Vt3 + tid * 16);
    __syncthreads();
#pragma unroll
    for (int nf = 0; nf < 4; ++nf) {
      int row = nf * 16 + lr;
      f32x4 cc = {0.f, 0.f, 0.f, 0.f};
      cc = mfma3(aqh0, aql0, *(const bf16x8*)(KsH + KB(row, q4 * 16)),
                 *(const bf16x8*)(KsL + KB(row, q4 * 16)), cc);
      cc = mfma3(aqh1, aql1, *(const bf16x8*)(KsH + KB(row, 64 + q4 * 16)),
                 *(const bf16x8*)(KsL + KB(row, 64 + q4 * 16)), cc);
#pragma unroll
      for (int r = 0; r < 4; ++r) {
        float p = __expf(cc[r] * 8.f - m_r[r]) * inv_l[r];
        PsH[w][q4 * 4 + r][nf * 16 + lr] = (__bf16)p;
        int arow = rb * 128 + w * 16 + q4 * 4 + r;
        attn_out[((size_t)(g * 1024 + arow)) * 1024 + kt * 64 + nf * 16 + lr] = p;
      }
    }
    // PV: PsH[w] is same-wave data; Vt staged this iteration
#pragma unroll
    for (int kk = 0; kk < 2; ++kk) {
      bf16x8 ph = *(const bf16x8*)&PsH[w][lr][kk * 32 + q4 * 8];
#pragma unroll
      for (int cf = 0; cf < 4; ++cf) {
        bf16x8 vt = *(const bf16x8*)(Vt + KB(cf * 16 + lr, kk * 64 + q4 * 16));
        co[cf] = MFMA(ph, vt, co[cf]);
      }
    }
  }
#pragma unroll
  for (int cf = 0; cf < 4; ++cf)
#pragma unroll
    for (int r = 0; r < 4; ++r) {
      int i = rb * 128 + w * 16 + q4 * 4 + r;
      ctx_out[((size_t)(g * 1024 + i)) * 64 + cf * 16 + lr] = (__bf16)co[cf][r];
    }
}

// ---------------------------------------------------------------------------
// m97-structure bf16 GEMM: C = A[MxK] * Bt[NxK]^T + bias (+Res).
// Tile BM x 128, BK=64, 4 waves. 1D grid with XCD-chunked swizzle.
// EPI 0: Outf = acc + bias + Res (f32).  EPI 1: Outb = bf16(relu(acc+bias)).
// ---------------------------------------------------------------------------
template <int EPI, int BM>
__global__ __launch_bounds__(256) void gemm_bt(
    const __bf16* __restrict__ A, const __bf16* __restrict__ Bt,
    const float* __restrict__ bias, const float* __restrict__ Res,
    float* __restrict__ Outf, __bf16* __restrict__ Outb,
    int M, int N, int K, int nbx)
{
  constexpr int MF = BM / 32;
  __shared__ __attribute__((aligned(16))) __bf16 sm[BM * 64 + 8192];
  const int tid = threadIdx.x;
  const int l = tid & 63, w = tid >> 6;
  const int lr = l & 15, lkb = (l >> 4) * 8;
  const int nwg = gridDim.x;
  const int swz = (blockIdx.x & 7) * (nwg >> 3) + (blockIdx.x >> 3);
  const int m0 = (swz / nbx) * BM, n0 = (swz % nbx) * 128;
  const int wr = (w >> 1) * (BM / 2), wc = (w & 1) * 64;
  LDS_AS char* sm3 = (LDS_AS char*)sm;

  f32x4 acc[MF][4];
  f32x4 zero = {0.f, 0.f, 0.f, 0.f};
#pragma unroll
  for (int m = 0; m < MF; ++m)
#pragma unroll
    for (int n = 0; n < 4; ++n) acc[m][n] = zero;

  const int nkt = K >> 6;
  for (int kt = 0; kt < nkt; ++kt) {
    __syncthreads();
#pragma unroll
    for (int it = 0; it < MF; ++it) {
      int slot = it * 256 + tid;
      int row = slot >> 3, cb = slot & 7;
      gld_lds16(&A[(size_t)(m0 + row) * K + kt * 64 + cb * 8], sm3 + slot * 16);
    }
#pragma unroll
    for (int it = 0; it < 4; ++it) {
      int slot = it * 256 + tid;
      int row = slot >> 3, cb = slot & 7;
      gld_lds16(&Bt[(size_t)(n0 + row) * K + kt * 64 + cb * 8],
                sm3 + BM * 128 + slot * 16);
    }
    __syncthreads();
#pragma unroll
    for (int kk = 0; kk < 2; ++kk) {
      bf16x8 a[MF], b[4];
#pragma unroll
      for (int m = 0; m < MF; ++m)
        a[m] = *(const bf16x8*)&sm[(wr + m * 16 + lr) * 64 + kk * 32 + lkb];
#pragma unroll
      for (int n = 0; n < 4; ++n)
        b[n] = *(const bf16x8*)&sm[BM * 64 + (wc + n * 16 + lr) * 64 + kk * 32 + lkb];
#pragma unroll
      for (int m = 0; m < MF; ++m)
#pragma unroll
        for (int n = 0; n < 4; ++n) acc[m][n] = MFMA(a[m], b[n], acc[m][n]);
    }
  }

#pragma unroll
  for (int n = 0; n < 4; ++n) {
    int gcol = n0 + wc + n * 16 + lr;
    float bc = bias[gcol];
#pragma unroll
    for (int m = 0; m < MF; ++m) {
      int grow = m0 + wr + m * 16 + (l >> 4) * 4;
#pragma unroll
      for (int r = 0; r < 4; ++r) {
        float v = acc[m][n][r] + bc;
        size_t o = (size_t)(grow + r) * N + gcol;
        if (EPI == 1) {
          Outb[o] = (__bf16)fmaxf(v, 0.f);
        } else {
          Outf[o] = v + Res[o];
        }
      }
    }
  }
}

// ---------------------------------------------------------------------------
// 32x32 transpose, f32 in -> bf16 out: out[C x R] = bf16(in[R x C]^T)
// ---------------------------------------------------------------------------
__global__ __launch_bounds__(256) void transpose_f32_bf16(
    const float* __restrict__ in, __bf16* __restrict__ out, int R, int C)
{
  __shared__ float tile[32][33];
  int bx = blockIdx.x * 32, by = blockIdx.y * 32;
  int tx = threadIdx.x & 31, ty = threadIdx.x >> 5;
  for (int i = ty; i < 32; i += 8)
    tile[i][tx] = in[(size_t)(by + i) * C + bx + tx];
  __syncthreads();
  for (int i = ty; i < 32; i += 8)
    out[(size_t)(bx + i) * R + by + tx] = (__bf16)tile[tx][i];
}

// ---------------------------------------------------------------------------
// LayerNorm over D=1024, one block per row; optional bf16 side output.
// ---------------------------------------------------------------------------
template <int SPLIT>
__global__ __launch_bounds__(256) void ln_split(
    const float* __restrict__ in, const float* __restrict__ gam,
    const float* __restrict__ bet, float* __restrict__ out,
    __bf16* __restrict__ outB)
{
  __shared__ float red[8];
  const int row = blockIdx.x, t = threadIdx.x;
  const float* rp = in + (size_t)row * 1024;
  f32x4 v = ((const f32x4*)rp)[t];
  float s = 0.f, ss = 0.f;
#pragma unroll
  for (int j = 0; j < 4; ++j) {
    s += v[j];
    ss += v[j] * v[j];
  }
#pragma unroll
  for (int o = 1; o < 64; o <<= 1) {
    s += __shfl_xor(s, o, 64);
    ss += __shfl_xor(ss, o, 64);
  }
  int w = t >> 6, l = t & 63;
  if (l == 0) { red[w] = s; red[4 + w] = ss; }
  __syncthreads();
  float S = red[0] + red[1] + red[2] + red[3];
  float SS = red[4] + red[5] + red[6] + red[7];
  float mean = S * (1.f / 1024.f);
  float var = SS * (1.f / 1024.f) - mean * mean;
  float rstd = rsqrtf(var + 1e-5f);
  f32x4 ov;
#pragma unroll
  for (int j = 0; j < 4; ++j) {
    int col = t * 4 + j;
    ov[j] = (v[j] - mean) * rstd * gam[col] + bet[col];
  }
  ((f32x4*)(out + (size_t)row * 1024))[t] = ov;
  if (SPLIT) {
    bf16x4 ob;
#pragma unroll
    for (int j = 0; j < 4; ++j) ob[j] = (__bf16)ov[j];
    *(bf16x4*)&outB[(size_t)row * 1024 + t * 4] = ob;
  }
}

// ---------------------------------------------------------------------------
extern "C" void kernel_launch(void* const* d_in, const int* in_sizes, int n_in,
                              void* d_out, int out_size, void* d_ws, size_t ws_size,
                              hipStream_t stream) {
  const float* k_in = (const float*)d_in[0];
  const float* v_in = (const float*)d_in[1];
  const float* q_in = (const float*)d_in[2];
  const float* r_in = (const float*)d_in[3];
  const float* Wf = (const float*)d_in[4];
  const float* bf = (const float*)d_in[5];
  const float* g1 = (const float*)d_in[6];
  const float* b1 = (const float*)d_in[7];
  const float* W1 = (const float*)d_in[8];
  const float* bw1 = (const float*)d_in[9];
  const float* W2 = (const float*)d_in[10];
  const float* bw2 = (const float*)d_in[11];
  const float* g2 = (const float*)d_in[12];
  const float* b2 = (const float*)d_in[13];

  float* out0 = (float*)d_out;          // [4096,1024]
  float* attn = out0 + 4194304;         // [64,1024,1024]

  char* W = (char*)d_ws;
  const size_t MB = 1024 * 1024;
  char* KHimg = W + 0;                   // 8MB
  char* KLimg = W + 8 * MB;              // 8MB
  char* VTimg = W + 16 * MB;             // 8MB
  __bf16* WFT = (__bf16*)(W + 24 * MB);  // 2MB
  __bf16* W1T = (__bf16*)(W + 26 * MB);  // 8MB
  __bf16* W2T = (__bf16*)(W + 34 * MB);  // 8MB
  __bf16* CTX = (__bf16*)(W + 42 * MB);  // 8MB
  __bf16* Xb = (__bf16*)(W + 50 * MB);   // 8MB
  __bf16* Hb = (__bf16*)(W + 58 * MB);   // 32MB
  float* T1 = (float*)(W + 90 * MB);     // 16MB (reused as T2)
  float* X = (float*)(W + 106 * MB);     // 16MB
  float* T2 = T1;

  prep_k<<<1024, 256, 0, stream>>>(k_in, KHimg, KLimg);
  prep_v<<<1024, 256, 0, stream>>>(q_in, VTimg);
  transpose_f32_bf16<<<dim3(32, 32), 256, 0, stream>>>(Wf, WFT, 1024, 1024);
  transpose_f32_bf16<<<dim3(128, 32), 256, 0, stream>>>(W1, W1T, 1024, 4096);
  transpose_f32_bf16<<<dim3(32, 128), 256, 0, stream>>>(W2, W2T, 4096, 1024);

  attn_v4<<<512, 512, 0, stream>>>(v_in, KHimg, KLimg, VTimg, attn, CTX);

  // t1 = r + ctx @ Wf + bf
  gemm_bt<0, 64><<<512, 256, 0, stream>>>(CTX, WFT, bf, r_in, T1, nullptr,
                                          4096, 1024, 1024, 8);
  ln_split<1><<<4096, 256, 0, stream>>>(T1, g1, b1, X, Xb);
  // h = relu(x @ W1 + bw1) -> bf16
  gemm_bt<1, 128><<<1024, 256, 0, stream>>>(Xb, W1T, bw1, nullptr, nullptr, Hb,
                                            4096, 4096, 1024, 32);
  // t2 = x + h @ W2 + bw2
  gemm_bt<0, 64><<<512, 256, 0, stream>>>(Hb, W2T, bw2, X, T2, nullptr,
                                          4096, 1024, 4096, 8);
  ln_split<0><<<4096, 256, 0, stream>>>(T2, g2, b2, out0, nullptr);
}

// Round 6
// 346.006 us; speedup vs baseline: 1.9517x; 1.0586x over previous
//
#include <hip/hip_runtime.h>
#include <hip/hip_bf16.h>
#include <cstdint>

typedef __attribute__((ext_vector_type(8))) __bf16 bf16x8;
typedef __attribute__((ext_vector_type(4))) __bf16 bf16x4;
typedef __attribute__((ext_vector_type(4))) float f32x4;
typedef unsigned int uint32;
typedef unsigned short uint16;

#define LDS_AS __attribute__((address_space(3)))
#define GLB_AS __attribute__((address_space(1)))

static __device__ __forceinline__ void gld_lds16(const void* g, LDS_AS char* l) {
  __builtin_amdgcn_global_load_lds((const GLB_AS uint32*)g, (LDS_AS uint32*)l, 16, 0, 0);
}

#define MFMA(a, b, c) __builtin_amdgcn_mfma_f32_16x16x32_bf16((a), (b), (c), 0, 0, 0)

// 3-term split-bf16 MFMA: A*B ~= Ah*Bh + Al*Bh + Ah*Bl
static __device__ __forceinline__ f32x4 mfma3(bf16x8 ah, bf16x8 al, bf16x8 bh,
                                              bf16x8 bl, f32x4 c) {
  c = MFMA(ah, bh, c);
  c = MFMA(al, bh, c);
  c = MFMA(ah, bl, c);
  return c;
}

static __device__ __forceinline__ uint32 pack_bf16(float a, float b) {
  __bf16 ha = (__bf16)a, hb = (__bf16)b;
  return (uint32)__builtin_bit_cast(uint16, ha) |
         ((uint32)__builtin_bit_cast(uint16, hb) << 16);
}

// XOR swizzle: spreads stride-128B rows across banks (T2, rule #21 both-sides)
#define KB(row, colbyte) ((((row) * 128 + (colbyte))) ^ (((row) & 7) << 4))

// ---------------------------------------------------------------------------
// prep_kv: builds per-(head,tile) swizzled LDS images.
//  blocks 0..1023:   K f32 -> split bf16 hi/lo images KH/KL (8192 B each)
//  blocks 1024..2047: V f32 -> V^T image, k-pairs packed u32
// ---------------------------------------------------------------------------
__global__ __launch_bounds__(256) void prep_kv(const float* __restrict__ K,
                                               const float* __restrict__ V,
                                               char* __restrict__ KH,
                                               char* __restrict__ KL,
                                               char* __restrict__ VT) {
  int b = blockIdx.x;
  if (b < 1024) {
    int kt = b & 15, h = b >> 4;
    const float* src = K + (size_t)h * 65536 + kt * 4096;
    char* dh = KH + (size_t)(h * 16 + kt) * 8192;
    char* dl = KL + (size_t)(h * 16 + kt) * 8192;
    int r = threadIdx.x >> 2, cq = threadIdx.x & 3;
    const float* sp = src + r * 64 + cq * 16;
    bf16x8 h0, l0, h1, l1;
#pragma unroll
    for (int j = 0; j < 8; ++j) {
      float x0 = sp[j], x1 = sp[8 + j];
      __bf16 a = (__bf16)x0, bb = (__bf16)x1;
      h0[j] = a; l0[j] = (__bf16)(x0 - (float)a);
      h1[j] = bb; l1[j] = (__bf16)(x1 - (float)bb);
    }
    int sw = (r & 7) << 4;
    int o0 = (r * 128 + cq * 32) ^ sw;
    int o1 = (r * 128 + cq * 32 + 16) ^ sw;
    *(bf16x8*)(dh + o0) = h0;
    *(bf16x8*)(dh + o1) = h1;
    *(bf16x8*)(dl + o0) = l0;
    *(bf16x8*)(dl + o1) = l1;
  } else {
    b -= 1024;
    int kt = b & 15, h = b >> 4;
    const float* src = V + (size_t)h * 65536 + kt * 4096;
    char* dv = VT + (size_t)(h * 16 + kt) * 8192;
    int kp = threadIdx.x >> 3, dq = threadIdx.x & 7;
    const float* s0 = src + (2 * kp) * 64 + dq * 8;
    const float* s1 = s0 + 64;
#pragma unroll
    for (int j = 0; j < 8; ++j) {
      uint32 pk = pack_bf16(s0[j], s1[j]);
      int d = dq * 8 + j;
      *(uint32*)(dv + ((d * 128 + kp * 4) ^ ((d & 7) << 4))) = pk;
    }
  }
}

// ---------------------------------------------------------------------------
// Attention v5: block = (head g, 128-row q block rb), 8 waves x 16 q rows.
// Double-buffered DMA staging with raw s_barrier + counted vmcnt (T3-min).
// Q = v_input, K = k_input, V = q_input (reference signature quirk).
// ---------------------------------------------------------------------------
__global__ __launch_bounds__(512, 4) void attn_v5(
    const float* __restrict__ Qin, const char* __restrict__ KHimg,
    const char* __restrict__ KLimg, const char* __restrict__ VTimg,
    float* __restrict__ attn_out, __bf16* __restrict__ ctx_out)
{
  __shared__ __attribute__((aligned(16))) char KsH[2][8192];
  __shared__ __attribute__((aligned(16))) char KsL[2][8192];
  __shared__ __attribute__((aligned(16))) char Vt[2][8192];
  __shared__ __attribute__((aligned(16))) __bf16 PsH[8][16][72];

  const int tid = threadIdx.x;
  const int l = tid & 63, w = tid >> 6;
  const int lr = l & 15, q4 = l >> 4;
  const int swz = (blockIdx.x & 7) * 64 + (blockIdx.x >> 3);  // XCD chunking
  const int g = swz >> 3, rb = swz & 7;
  const size_t base = (size_t)g * 65536;
  const char* khb = KHimg + (size_t)g * 131072;
  const char* klb = KLimg + (size_t)g * 131072;
  const char* vtb = VTimg + (size_t)g * 131072;

  // Q fragments (per-lane row = rb*128 + w*16 + lr), split hi/lo
  const float* qp = Qin + base + (size_t)(rb * 128 + w * 16 + lr) * 64;
  f32x4 qv[4];
#pragma unroll
  for (int j = 0; j < 2; ++j) {
    qv[j] = *(const f32x4*)&qp[q4 * 8 + j * 4];
    qv[2 + j] = *(const f32x4*)&qp[32 + q4 * 8 + j * 4];
  }

  // stage pass-1 tile 0
  gld_lds16(khb + 0 * 8192 + tid * 16, (LDS_AS char*)&KsH[0][0] + tid * 16);
  gld_lds16(klb + 0 * 8192 + tid * 16, (LDS_AS char*)&KsL[0][0] + tid * 16);

  bf16x8 aqh0, aql0, aqh1, aql1;
#pragma unroll
  for (int j = 0; j < 8; ++j) {
    float x0 = qv[j >> 2][j & 3];
    float x1 = qv[2 + (j >> 2)][j & 3];
    __bf16 h0 = (__bf16)x0, h1 = (__bf16)x1;
    aqh0[j] = h0; aql0[j] = (__bf16)(x0 - (float)h0);
    aqh1[j] = h1; aql1[j] = (__bf16)(x1 - (float)h1);
  }

  float m_r[4], l_r[4];
#pragma unroll
  for (int r = 0; r < 4; ++r) { m_r[r] = -1e30f; l_r[r] = 0.f; }

  // ---- pass 1: stats (2 loads/tile, double-buffered) ----
  for (int kt = 0; kt < 16; ++kt) {
    const int buf = kt & 1;
    if (kt < 15) {
      gld_lds16(khb + (kt + 1) * 8192 + tid * 16,
                (LDS_AS char*)&KsH[buf ^ 1][0] + tid * 16);
      gld_lds16(klb + (kt + 1) * 8192 + tid * 16,
                (LDS_AS char*)&KsL[buf ^ 1][0] + tid * 16);
      asm volatile("s_waitcnt vmcnt(2)" ::: "memory");
    } else {
      asm volatile("s_waitcnt vmcnt(0)" ::: "memory");
    }
    __builtin_amdgcn_s_barrier();
    const char* ksh = KsH[buf];
    const char* ksl = KsL[buf];
    f32x4 c[4];
#pragma unroll
    for (int nf = 0; nf < 4; ++nf) {
      int row = nf * 16 + lr;
      f32x4 cc = {0.f, 0.f, 0.f, 0.f};
      cc = mfma3(aqh0, aql0, *(const bf16x8*)(ksh + KB(row, q4 * 16)),
                 *(const bf16x8*)(ksl + KB(row, q4 * 16)), cc);
      cc = mfma3(aqh1, aql1, *(const bf16x8*)(ksh + KB(row, 64 + q4 * 16)),
                 *(const bf16x8*)(ksl + KB(row, 64 + q4 * 16)), cc);
      c[nf] = cc;
    }
#pragma unroll
    for (int r = 0; r < 4; ++r) {
      float s0 = c[0][r] * 8.f, s1 = c[1][r] * 8.f;
      float s2 = c[2][r] * 8.f, s3 = c[3][r] * 8.f;
      float tm = fmaxf(fmaxf(s0, s1), fmaxf(s2, s3));
#pragma unroll
      for (int o = 1; o < 16; o <<= 1) tm = fmaxf(tm, __shfl_xor(tm, o, 64));
      float mnew = fmaxf(m_r[r], tm);
      float se = __expf(s0 - mnew) + __expf(s1 - mnew) +
                 __expf(s2 - mnew) + __expf(s3 - mnew);
#pragma unroll
      for (int o = 1; o < 16; o <<= 1) se += __shfl_xor(se, o, 64);
      l_r[r] = l_r[r] * __expf(m_r[r] - mnew) + se;
      m_r[r] = mnew;
    }
    __builtin_amdgcn_s_barrier();
  }
  float inv_l[4];
#pragma unroll
  for (int r = 0; r < 4; ++r) inv_l[r] = 1.f / l_r[r];

  f32x4 co[4];
#pragma unroll
  for (int cf = 0; cf < 4; ++cf) co[cf] = (f32x4){0.f, 0.f, 0.f, 0.f};

  // stage pass-2 tile 0 (K + V)
  gld_lds16(khb + 0 * 8192 + tid * 16, (LDS_AS char*)&KsH[0][0] + tid * 16);
  gld_lds16(klb + 0 * 8192 + tid * 16, (LDS_AS char*)&KsL[0][0] + tid * 16);
  gld_lds16(vtb + 0 * 8192 + tid * 16, (LDS_AS char*)&Vt[0][0] + tid * 16);

  // ---- pass 2: P (f32 attn out + bf16 Ps) + PV ----
  // vmcnt ledger per lane: 3 loads/STAGE, 16 attn stores/tile.
  for (int kt = 0; kt < 16; ++kt) {
    const int buf = kt & 1;
    if (kt < 15) {
      gld_lds16(khb + (kt + 1) * 8192 + tid * 16,
                (LDS_AS char*)&KsH[buf ^ 1][0] + tid * 16);
      gld_lds16(klb + (kt + 1) * 8192 + tid * 16,
                (LDS_AS char*)&KsL[buf ^ 1][0] + tid * 16);
      gld_lds16(vtb + (kt + 1) * 8192 + tid * 16,
                (LDS_AS char*)&Vt[buf ^ 1][0] + tid * 16);
    }
    if (kt == 0) {
      asm volatile("s_waitcnt vmcnt(3)" ::: "memory");
    } else if (kt < 15) {
      asm volatile("s_waitcnt vmcnt(19)" ::: "memory");
    } else {
      asm volatile("s_waitcnt vmcnt(16)" ::: "memory");
    }
    __builtin_amdgcn_s_barrier();
    const char* ksh = KsH[buf];
    const char* ksl = KsL[buf];
    const char* vts = Vt[buf];
#pragma unroll
    for (int nf = 0; nf < 4; ++nf) {
      int row = nf * 16 + lr;
      f32x4 cc = {0.f, 0.f, 0.f, 0.f};
      cc = mfma3(aqh0, aql0, *(const bf16x8*)(ksh + KB(row, q4 * 16)),
                 *(const bf16x8*)(ksl + KB(row, q4 * 16)), cc);
      cc = mfma3(aqh1, aql1, *(const bf16x8*)(ksh + KB(row, 64 + q4 * 16)),
                 *(const bf16x8*)(ksl + KB(row, 64 + q4 * 16)), cc);
#pragma unroll
      for (int r = 0; r < 4; ++r) {
        float p = __expf(cc[r] * 8.f - m_r[r]) * inv_l[r];
        PsH[w][q4 * 4 + r][nf * 16 + lr] = (__bf16)p;
        int arow = rb * 128 + w * 16 + q4 * 4 + r;
        attn_out[((size_t)(g * 1024 + arow)) * 1024 + kt * 64 + nf * 16 + lr] = p;
      }
    }
    // PV: PsH[w] same-wave; Vt[buf] staged this tile
#pragma unroll
    for (int kk = 0; kk < 2; ++kk) {
      bf16x8 ph = *(const bf16x8*)&PsH[w][lr][kk * 32 + q4 * 8];
#pragma unroll
      for (int cf = 0; cf < 4; ++cf) {
        bf16x8 vt = *(const bf16x8*)(vts + KB(cf * 16 + lr, kk * 64 + q4 * 16));
        co[cf] = MFMA(ph, vt, co[cf]);
      }
    }
    __builtin_amdgcn_s_barrier();
  }
#pragma unroll
  for (int cf = 0; cf < 4; ++cf)
#pragma unroll
    for (int r = 0; r < 4; ++r) {
      int i = rb * 128 + w * 16 + q4 * 4 + r;
      ctx_out[((size_t)(g * 1024 + i)) * 64 + cf * 16 + lr] = (__bf16)co[cf][r];
    }
}

// ---------------------------------------------------------------------------
// m97-structure bf16 GEMM: C = A[MxK] * Bt[NxK]^T + bias (+Res).
// Tile BM x 128, BK=64, 4 waves. 1D grid with XCD-chunked swizzle.
// EPI 0: Outf = acc+bias+Res(f32). EPI 1: Outb = bf16(relu(acc+bias)).
// EPI 2: Outf = acc+bias+ResB(bf16).
// ---------------------------------------------------------------------------
template <int EPI, int BM>
__global__ __launch_bounds__(256) void gemm_bt(
    const __bf16* __restrict__ A, const __bf16* __restrict__ Bt,
    const float* __restrict__ bias, const float* __restrict__ Res,
    const __bf16* __restrict__ ResB, float* __restrict__ Outf,
    __bf16* __restrict__ Outb, int M, int N, int K, int nbx)
{
  constexpr int MF = BM / 32;
  __shared__ __attribute__((aligned(16))) __bf16 sm[BM * 64 + 8192];
  const int tid = threadIdx.x;
  const int l = tid & 63, w = tid >> 6;
  const int lr = l & 15, lkb = (l >> 4) * 8;
  const int nwg = gridDim.x;
  const int swz = (blockIdx.x & 7) * (nwg >> 3) + (blockIdx.x >> 3);
  const int m0 = (swz / nbx) * BM, n0 = (swz % nbx) * 128;
  const int wr = (w >> 1) * (BM / 2), wc = (w & 1) * 64;
  LDS_AS char* sm3 = (LDS_AS char*)sm;

  f32x4 acc[MF][4];
  f32x4 zero = {0.f, 0.f, 0.f, 0.f};
#pragma unroll
  for (int m = 0; m < MF; ++m)
#pragma unroll
    for (int n = 0; n < 4; ++n) acc[m][n] = zero;

  const int nkt = K >> 6;
  for (int kt = 0; kt < nkt; ++kt) {
    __syncthreads();
#pragma unroll
    for (int it = 0; it < MF; ++it) {
      int slot = it * 256 + tid;
      int row = slot >> 3, cb = slot & 7;
      gld_lds16(&A[(size_t)(m0 + row) * K + kt * 64 + cb * 8], sm3 + slot * 16);
    }
#pragma unroll
    for (int it = 0; it < 4; ++it) {
      int slot = it * 256 + tid;
      int row = slot >> 3, cb = slot & 7;
      gld_lds16(&Bt[(size_t)(n0 + row) * K + kt * 64 + cb * 8],
                sm3 + BM * 128 + slot * 16);
    }
    __syncthreads();
#pragma unroll
    for (int kk = 0; kk < 2; ++kk) {
      bf16x8 a[MF], b[4];
#pragma unroll
      for (int m = 0; m < MF; ++m)
        a[m] = *(const bf16x8*)&sm[(wr + m * 16 + lr) * 64 + kk * 32 + lkb];
#pragma unroll
      for (int n = 0; n < 4; ++n)
        b[n] = *(const bf16x8*)&sm[BM * 64 + (wc + n * 16 + lr) * 64 + kk * 32 + lkb];
#pragma unroll
      for (int m = 0; m < MF; ++m)
#pragma unroll
        for (int n = 0; n < 4; ++n) acc[m][n] = MFMA(a[m], b[n], acc[m][n]);
    }
  }

#pragma unroll
  for (int n = 0; n < 4; ++n) {
    int gcol = n0 + wc + n * 16 + lr;
    float bc = bias[gcol];
#pragma unroll
    for (int m = 0; m < MF; ++m) {
      int grow = m0 + wr + m * 16 + (l >> 4) * 4;
#pragma unroll
      for (int r = 0; r < 4; ++r) {
        float v = acc[m][n][r] + bc;
        size_t o = (size_t)(grow + r) * N + gcol;
        if (EPI == 1) {
          Outb[o] = (__bf16)fmaxf(v, 0.f);
        } else if (EPI == 0) {
          Outf[o] = v + Res[o];
        } else {
          Outf[o] = v + (float)ResB[o];
        }
      }
    }
  }
}

// ---------------------------------------------------------------------------
// 32x32 transpose, f32 in -> bf16 out: out[C x R] = bf16(in[R x C]^T)
// ---------------------------------------------------------------------------
__global__ __launch_bounds__(256) void transpose_f32_bf16(
    const float* __restrict__ in, __bf16* __restrict__ out, int R, int C)
{
  __shared__ float tile[32][33];
  int bx = blockIdx.x * 32, by = blockIdx.y * 32;
  int tx = threadIdx.x & 31, ty = threadIdx.x >> 5;
  for (int i = ty; i < 32; i += 8)
    tile[i][tx] = in[(size_t)(by + i) * C + bx + tx];
  __syncthreads();
  for (int i = ty; i < 32; i += 8)
    out[(size_t)(bx + i) * R + by + tx] = (__bf16)tile[tx][i];
}

// ---------------------------------------------------------------------------
// LayerNorm over D=1024, one block per row. OUTF: f32 out; OUTB: bf16 out.
// ---------------------------------------------------------------------------
template <int OUTF, int OUTB>
__global__ __launch_bounds__(256) void ln_kernel(
    const float* __restrict__ in, const float* __restrict__ gam,
    const float* __restrict__ bet, float* __restrict__ out,
    __bf16* __restrict__ outB)
{
  __shared__ float red[8];
  const int row = blockIdx.x, t = threadIdx.x;
  const float* rp = in + (size_t)row * 1024;
  f32x4 v = ((const f32x4*)rp)[t];
  float s = 0.f, ss = 0.f;
#pragma unroll
  for (int j = 0; j < 4; ++j) {
    s += v[j];
    ss += v[j] * v[j];
  }
#pragma unroll
  for (int o = 1; o < 64; o <<= 1) {
    s += __shfl_xor(s, o, 64);
    ss += __shfl_xor(ss, o, 64);
  }
  int w = t >> 6, l = t & 63;
  if (l == 0) { red[w] = s; red[4 + w] = ss; }
  __syncthreads();
  float S = red[0] + red[1] + red[2] + red[3];
  float SS = red[4] + red[5] + red[6] + red[7];
  float mean = S * (1.f / 1024.f);
  float var = SS * (1.f / 1024.f) - mean * mean;
  float rstd = rsqrtf(var + 1e-5f);
  f32x4 ov;
#pragma unroll
  for (int j = 0; j < 4; ++j) {
    int col = t * 4 + j;
    ov[j] = (v[j] - mean) * rstd * gam[col] + bet[col];
  }
  if (OUTF) ((f32x4*)(out + (size_t)row * 1024))[t] = ov;
  if (OUTB) {
    bf16x4 ob;
#pragma unroll
    for (int j = 0; j < 4; ++j) ob[j] = (__bf16)ov[j];
    *(bf16x4*)&outB[(size_t)row * 1024 + t * 4] = ob;
  }
}

// ---------------------------------------------------------------------------
extern "C" void kernel_launch(void* const* d_in, const int* in_sizes, int n_in,
                              void* d_out, int out_size, void* d_ws, size_t ws_size,
                              hipStream_t stream) {
  const float* k_in = (const float*)d_in[0];
  const float* v_in = (const float*)d_in[1];
  const float* q_in = (const float*)d_in[2];
  const float* r_in = (const float*)d_in[3];
  const float* Wf = (const float*)d_in[4];
  const float* bf = (const float*)d_in[5];
  const float* g1 = (const float*)d_in[6];
  const float* b1 = (const float*)d_in[7];
  const float* W1 = (const float*)d_in[8];
  const float* bw1 = (const float*)d_in[9];
  const float* W2 = (const float*)d_in[10];
  const float* bw2 = (const float*)d_in[11];
  const float* g2 = (const float*)d_in[12];
  const float* b2 = (const float*)d_in[13];

  float* out0 = (float*)d_out;          // [4096,1024]
  float* attn = out0 + 4194304;         // [64,1024,1024]

  char* W = (char*)d_ws;
  const size_t MB = 1024 * 1024;
  char* KHimg = W + 0;                   // 8MB
  char* KLimg = W + 8 * MB;              // 8MB
  char* VTimg = W + 16 * MB;             // 8MB
  __bf16* WFT = (__bf16*)(W + 24 * MB);  // 2MB
  __bf16* W1T = (__bf16*)(W + 26 * MB);  // 8MB
  __bf16* W2T = (__bf16*)(W + 34 * MB);  // 8MB
  __bf16* CTX = (__bf16*)(W + 42 * MB);  // 8MB
  __bf16* Xb = (__bf16*)(W + 50 * MB);   // 8MB
  __bf16* Hb = (__bf16*)(W + 58 * MB);   // 32MB
  float* T1 = (float*)(W + 90 * MB);     // 16MB (reused as T2)
  float* T2 = T1;

  prep_kv<<<2048, 256, 0, stream>>>(k_in, q_in, KHimg, KLimg, VTimg);
  transpose_f32_bf16<<<dim3(32, 32), 256, 0, stream>>>(Wf, WFT, 1024, 1024);
  transpose_f32_bf16<<<dim3(128, 32), 256, 0, stream>>>(W1, W1T, 1024, 4096);
  transpose_f32_bf16<<<dim3(32, 128), 256, 0, stream>>>(W2, W2T, 4096, 1024);

  attn_v5<<<512, 512, 0, stream>>>(v_in, KHimg, KLimg, VTimg, attn, CTX);

  // t1 = r + ctx @ Wf + bf
  gemm_bt<0, 64><<<512, 256, 0, stream>>>(CTX, WFT, bf, r_in, nullptr, T1,
                                          nullptr, 4096, 1024, 1024, 8);
  // x = LN(t1) -> bf16 only
  ln_kernel<0, 1><<<4096, 256, 0, stream>>>(T1, g1, b1, nullptr, Xb);
  // h = relu(x @ W1 + bw1) -> bf16
  gemm_bt<1, 128><<<1024, 256, 0, stream>>>(Xb, W1T, bw1, nullptr, nullptr,
                                            nullptr, Hb, 4096, 4096, 1024, 32);
  // t2 = x + h @ W2 + bw2   (residual in bf16)
  gemm_bt<2, 64><<<512, 256, 0, stream>>>(Hb, W2T, bw2, nullptr, Xb, T2,
                                          nullptr, 4096, 1024, 4096, 8);
  ln_kernel<1, 0><<<4096, 256, 0, stream>>>(T2, g2, b2, out0, nullptr);
}

// Round 7
// 309.038 us; speedup vs baseline: 2.1851x; 1.1196x over previous
//
#include <hip/hip_runtime.h>
#include <hip/hip_bf16.h>
#include <cstdint>

typedef __attribute__((ext_vector_type(8))) __bf16 bf16x8;
typedef __attribute__((ext_vector_type(4))) __bf16 bf16x4;
typedef __attribute__((ext_vector_type(4))) float f32x4;
typedef unsigned int uint32;
typedef unsigned short uint16;

#define LDS_AS __attribute__((address_space(3)))
#define GLB_AS __attribute__((address_space(1)))

static __device__ __forceinline__ void gld_lds16(const void* g, LDS_AS char* l) {
  __builtin_amdgcn_global_load_lds((const GLB_AS uint32*)g, (LDS_AS uint32*)l, 16, 0, 0);
}

#define MFMA(a, b, c) __builtin_amdgcn_mfma_f32_16x16x32_bf16((a), (b), (c), 0, 0, 0)

// 3-term split-bf16 MFMA: A*B ~= Ah*Bh + Al*Bh + Ah*Bl
static __device__ __forceinline__ f32x4 mfma3(bf16x8 ah, bf16x8 al, bf16x8 bh,
                                              bf16x8 bl, f32x4 c) {
  c = MFMA(ah, bh, c);
  c = MFMA(al, bh, c);
  c = MFMA(ah, bl, c);
  return c;
}

static __device__ __forceinline__ uint32 pack_bf16(float a, float b) {
  __bf16 ha = (__bf16)a, hb = (__bf16)b;
  return (uint32)__builtin_bit_cast(uint16, ha) |
         ((uint32)__builtin_bit_cast(uint16, hb) << 16);
}

// XOR swizzle: spreads stride-128B rows across banks (T2, rule #21 both-sides)
#define KB(row, colbyte) ((((row) * 128 + (colbyte))) ^ (((row) & 7) << 4))

// ---------------------------------------------------------------------------
// prep_kv: builds per-(head,tile) swizzled LDS images.
//  blocks 0..1023:   K f32 -> split bf16 hi/lo images KH/KL (8192 B each)
//  blocks 1024..2047: V f32 -> V^T image, k-pairs packed u32
// ---------------------------------------------------------------------------
__global__ __launch_bounds__(256) void prep_kv(const float* __restrict__ K,
                                               const float* __restrict__ V,
                                               char* __restrict__ KH,
                                               char* __restrict__ KL,
                                               char* __restrict__ VT) {
  int b = blockIdx.x;
  if (b < 1024) {
    int kt = b & 15, h = b >> 4;
    const float* src = K + (size_t)h * 65536 + kt * 4096;
    char* dh = KH + (size_t)(h * 16 + kt) * 8192;
    char* dl = KL + (size_t)(h * 16 + kt) * 8192;
    int r = threadIdx.x >> 2, cq = threadIdx.x & 3;
    const float* sp = src + r * 64 + cq * 16;
    bf16x8 h0, l0, h1, l1;
#pragma unroll
    for (int j = 0; j < 8; ++j) {
      float x0 = sp[j], x1 = sp[8 + j];
      __bf16 a = (__bf16)x0, bb = (__bf16)x1;
      h0[j] = a; l0[j] = (__bf16)(x0 - (float)a);
      h1[j] = bb; l1[j] = (__bf16)(x1 - (float)bb);
    }
    int sw = (r & 7) << 4;
    int o0 = (r * 128 + cq * 32) ^ sw;
    int o1 = (r * 128 + cq * 32 + 16) ^ sw;
    *(bf16x8*)(dh + o0) = h0;
    *(bf16x8*)(dh + o1) = h1;
    *(bf16x8*)(dl + o0) = l0;
    *(bf16x8*)(dl + o1) = l1;
  } else {
    b -= 1024;
    int kt = b & 15, h = b >> 4;
    const float* src = V + (size_t)h * 65536 + kt * 4096;
    char* dv = VT + (size_t)(h * 16 + kt) * 8192;
    int kp = threadIdx.x >> 3, dq = threadIdx.x & 7;
    const float* s0 = src + (2 * kp) * 64 + dq * 8;
    const float* s1 = s0 + 64;
#pragma unroll
    for (int j = 0; j < 8; ++j) {
      uint32 pk = pack_bf16(s0[j], s1[j]);
      int d = dq * 8 + j;
      *(uint32*)(dv + ((d * 128 + kp * 4) ^ ((d & 7) << 4))) = pk;
    }
  }
}

// ---------------------------------------------------------------------------
// Attention v6: v5 + non-temporal P stores (don't thrash L2: keep K/V images
// resident per XCD). Block = (head g, 128-row q block rb), 8 waves x 16 rows.
// Q = v_input, K = k_input, V = q_input (reference signature quirk).
// ---------------------------------------------------------------------------
__global__ __launch_bounds__(512, 4) void attn_v6(
    const float* __restrict__ Qin, const char* __restrict__ KHimg,
    const char* __restrict__ KLimg, const char* __restrict__ VTimg,
    float* __restrict__ attn_out, __bf16* __restrict__ ctx_out)
{
  __shared__ __attribute__((aligned(16))) char KsH[2][8192];
  __shared__ __attribute__((aligned(16))) char KsL[2][8192];
  __shared__ __attribute__((aligned(16))) char Vt[2][8192];
  __shared__ __attribute__((aligned(16))) __bf16 PsH[8][16][72];

  const int tid = threadIdx.x;
  const int l = tid & 63, w = tid >> 6;
  const int lr = l & 15, q4 = l >> 4;
  const int swz = (blockIdx.x & 7) * 64 + (blockIdx.x >> 3);  // XCD chunking
  const int g = swz >> 3, rb = swz & 7;
  const size_t base = (size_t)g * 65536;
  const char* khb = KHimg + (size_t)g * 131072;
  const char* klb = KLimg + (size_t)g * 131072;
  const char* vtb = VTimg + (size_t)g * 131072;

  // Q fragments (per-lane row = rb*128 + w*16 + lr), split hi/lo
  const float* qp = Qin + base + (size_t)(rb * 128 + w * 16 + lr) * 64;
  f32x4 qv[4];
#pragma unroll
  for (int j = 0; j < 2; ++j) {
    qv[j] = *(const f32x4*)&qp[q4 * 8 + j * 4];
    qv[2 + j] = *(const f32x4*)&qp[32 + q4 * 8 + j * 4];
  }

  // stage pass-1 tile 0
  gld_lds16(khb + 0 * 8192 + tid * 16, (LDS_AS char*)&KsH[0][0] + tid * 16);
  gld_lds16(klb + 0 * 8192 + tid * 16, (LDS_AS char*)&KsL[0][0] + tid * 16);

  bf16x8 aqh0, aql0, aqh1, aql1;
#pragma unroll
  for (int j = 0; j < 8; ++j) {
    float x0 = qv[j >> 2][j & 3];
    float x1 = qv[2 + (j >> 2)][j & 3];
    __bf16 h0 = (__bf16)x0, h1 = (__bf16)x1;
    aqh0[j] = h0; aql0[j] = (__bf16)(x0 - (float)h0);
    aqh1[j] = h1; aql1[j] = (__bf16)(x1 - (float)h1);
  }

  float m_r[4], l_r[4];
#pragma unroll
  for (int r = 0; r < 4; ++r) { m_r[r] = -1e30f; l_r[r] = 0.f; }

  // ---- pass 1: stats (2 loads/tile, double-buffered) ----
  for (int kt = 0; kt < 16; ++kt) {
    const int buf = kt & 1;
    if (kt < 15) {
      gld_lds16(khb + (kt + 1) * 8192 + tid * 16,
                (LDS_AS char*)&KsH[buf ^ 1][0] + tid * 16);
      gld_lds16(klb + (kt + 1) * 8192 + tid * 16,
                (LDS_AS char*)&KsL[buf ^ 1][0] + tid * 16);
      asm volatile("s_waitcnt vmcnt(2)" ::: "memory");
    } else {
      asm volatile("s_waitcnt vmcnt(0)" ::: "memory");
    }
    __builtin_amdgcn_s_barrier();
    const char* ksh = KsH[buf];
    const char* ksl = KsL[buf];
    f32x4 c[4];
#pragma unroll
    for (int nf = 0; nf < 4; ++nf) {
      int row = nf * 16 + lr;
      f32x4 cc = {0.f, 0.f, 0.f, 0.f};
      cc = mfma3(aqh0, aql0, *(const bf16x8*)(ksh + KB(row, q4 * 16)),
                 *(const bf16x8*)(ksl + KB(row, q4 * 16)), cc);
      cc = mfma3(aqh1, aql1, *(const bf16x8*)(ksh + KB(row, 64 + q4 * 16)),
                 *(const bf16x8*)(ksl + KB(row, 64 + q4 * 16)), cc);
      c[nf] = cc;
    }
#pragma unroll
    for (int r = 0; r < 4; ++r) {
      float s0 = c[0][r] * 8.f, s1 = c[1][r] * 8.f;
      float s2 = c[2][r] * 8.f, s3 = c[3][r] * 8.f;
      float tm = fmaxf(fmaxf(s0, s1), fmaxf(s2, s3));
#pragma unroll
      for (int o = 1; o < 16; o <<= 1) tm = fmaxf(tm, __shfl_xor(tm, o, 64));
      float mnew = fmaxf(m_r[r], tm);
      float se = __expf(s0 - mnew) + __expf(s1 - mnew) +
                 __expf(s2 - mnew) + __expf(s3 - mnew);
#pragma unroll
      for (int o = 1; o < 16; o <<= 1) se += __shfl_xor(se, o, 64);
      l_r[r] = l_r[r] * __expf(m_r[r] - mnew) + se;
      m_r[r] = mnew;
    }
    __builtin_amdgcn_s_barrier();
  }
  float inv_l[4];
#pragma unroll
  for (int r = 0; r < 4; ++r) inv_l[r] = 1.f / l_r[r];

  f32x4 co[4];
#pragma unroll
  for (int cf = 0; cf < 4; ++cf) co[cf] = (f32x4){0.f, 0.f, 0.f, 0.f};

  // stage pass-2 tile 0 (K + V)
  gld_lds16(khb + 0 * 8192 + tid * 16, (LDS_AS char*)&KsH[0][0] + tid * 16);
  gld_lds16(klb + 0 * 8192 + tid * 16, (LDS_AS char*)&KsL[0][0] + tid * 16);
  gld_lds16(vtb + 0 * 8192 + tid * 16, (LDS_AS char*)&Vt[0][0] + tid * 16);

  // ---- pass 2: P (nt f32 attn out + bf16 Ps) + PV ----
  // vmcnt ledger per lane: 3 loads/STAGE, 16 attn stores/tile.
  for (int kt = 0; kt < 16; ++kt) {
    const int buf = kt & 1;
    if (kt < 15) {
      gld_lds16(khb + (kt + 1) * 8192 + tid * 16,
                (LDS_AS char*)&KsH[buf ^ 1][0] + tid * 16);
      gld_lds16(klb + (kt + 1) * 8192 + tid * 16,
                (LDS_AS char*)&KsL[buf ^ 1][0] + tid * 16);
      gld_lds16(vtb + (kt + 1) * 8192 + tid * 16,
                (LDS_AS char*)&Vt[buf ^ 1][0] + tid * 16);
    }
    if (kt == 0) {
      asm volatile("s_waitcnt vmcnt(3)" ::: "memory");
    } else if (kt < 15) {
      asm volatile("s_waitcnt vmcnt(19)" ::: "memory");
    } else {
      asm volatile("s_waitcnt vmcnt(16)" ::: "memory");
    }
    __builtin_amdgcn_s_barrier();
    const char* ksh = KsH[buf];
    const char* ksl = KsL[buf];
    const char* vts = Vt[buf];
#pragma unroll
    for (int nf = 0; nf < 4; ++nf) {
      int row = nf * 16 + lr;
      f32x4 cc = {0.f, 0.f, 0.f, 0.f};
      cc = mfma3(aqh0, aql0, *(const bf16x8*)(ksh + KB(row, q4 * 16)),
                 *(const bf16x8*)(ksl + KB(row, q4 * 16)), cc);
      cc = mfma3(aqh1, aql1, *(const bf16x8*)(ksh + KB(row, 64 + q4 * 16)),
                 *(const bf16x8*)(ksl + KB(row, 64 + q4 * 16)), cc);
#pragma unroll
      for (int r = 0; r < 4; ++r) {
        float p = __expf(cc[r] * 8.f - m_r[r]) * inv_l[r];
        PsH[w][q4 * 4 + r][nf * 16 + lr] = (__bf16)p;
        int arow = rb * 128 + w * 16 + q4 * 4 + r;
        __builtin_nontemporal_store(
            p, &attn_out[((size_t)(g * 1024 + arow)) * 1024 + kt * 64 + nf * 16 + lr]);
      }
    }
    // PV: PsH[w] same-wave; Vt[buf] staged this tile
#pragma unroll
    for (int kk = 0; kk < 2; ++kk) {
      bf16x8 ph = *(const bf16x8*)&PsH[w][lr][kk * 32 + q4 * 8];
#pragma unroll
      for (int cf = 0; cf < 4; ++cf) {
        bf16x8 vt = *(const bf16x8*)(vts + KB(cf * 16 + lr, kk * 64 + q4 * 16));
        co[cf] = MFMA(ph, vt, co[cf]);
      }
    }
    __builtin_amdgcn_s_barrier();
  }
#pragma unroll
  for (int cf = 0; cf < 4; ++cf)
#pragma unroll
    for (int r = 0; r < 4; ++r) {
      int i = rb * 128 + w * 16 + q4 * 4 + r;
      ctx_out[((size_t)(g * 1024 + i)) * 64 + cf * 16 + lr] = (__bf16)co[cf][r];
    }
}

// ---------------------------------------------------------------------------
// m97-structure bf16 GEMM: C = A[MxK] * Bt[NxK]^T (+bias) (+Res).
// Tile BM x 128, 4 waves, 1D grid with XCD-chunked swizzle.
// EPI 0: Outf = acc+bias+Res(f32). EPI 1: Outb = bf16(relu(acc+bias)).
// EPI 2: Outf = acc+bias+ResB(bf16). EPI 3: Outf = acc (pure partial).
// Kloop = #K elements this block accumulates (stride stays K).
// ---------------------------------------------------------------------------
template <int EPI, int BM>
__global__ __launch_bounds__(256) void gemm_bt(
    const __bf16* __restrict__ A, const __bf16* __restrict__ Bt,
    const float* __restrict__ bias, const float* __restrict__ Res,
    const __bf16* __restrict__ ResB, float* __restrict__ Outf,
    __bf16* __restrict__ Outb, int M, int N, int K, int Kloop, int nbx,
    int tiles_per_out)
{
  constexpr int MF = BM / 32;
  __shared__ __attribute__((aligned(16))) __bf16 sm[BM * 64 + 8192];
  const int tid = threadIdx.x;
  const int l = tid & 63, w = tid >> 6;
  const int lr = l & 15, lkb = (l >> 4) * 8;
  const int nwg = gridDim.x;
  const int swz = (blockIdx.x & 7) * (nwg >> 3) + (blockIdx.x >> 3);
  const int ks = swz / tiles_per_out;          // split-K slice
  const int tile = swz % tiles_per_out;
  const int m0 = (tile / nbx) * BM, n0 = (tile % nbx) * 128;
  const int kbase = ks * Kloop;
  const int wr = (w >> 1) * (BM / 2), wc = (w & 1) * 64;
  LDS_AS char* sm3 = (LDS_AS char*)sm;

  f32x4 acc[MF][4];
  f32x4 zero = {0.f, 0.f, 0.f, 0.f};
#pragma unroll
  for (int m = 0; m < MF; ++m)
#pragma unroll
    for (int n = 0; n < 4; ++n) acc[m][n] = zero;

  const int nkt = Kloop >> 6;
  for (int kt = 0; kt < nkt; ++kt) {
    __syncthreads();
#pragma unroll
    for (int it = 0; it < MF; ++it) {
      int slot = it * 256 + tid;
      int row = slot >> 3, cb = slot & 7;
      gld_lds16(&A[(size_t)(m0 + row) * K + kbase + kt * 64 + cb * 8],
                sm3 + slot * 16);
    }
#pragma unroll
    for (int it = 0; it < 4; ++it) {
      int slot = it * 256 + tid;
      int row = slot >> 3, cb = slot & 7;
      gld_lds16(&Bt[(size_t)(n0 + row) * K + kbase + kt * 64 + cb * 8],
                sm3 + BM * 128 + slot * 16);
    }
    __syncthreads();
#pragma unroll
    for (int kk = 0; kk < 2; ++kk) {
      bf16x8 a[MF], b[4];
#pragma unroll
      for (int m = 0; m < MF; ++m)
        a[m] = *(const bf16x8*)&sm[(wr + m * 16 + lr) * 64 + kk * 32 + lkb];
#pragma unroll
      for (int n = 0; n < 4; ++n)
        b[n] = *(const bf16x8*)&sm[BM * 64 + (wc + n * 16 + lr) * 64 + kk * 32 + lkb];
#pragma unroll
      for (int m = 0; m < MF; ++m)
#pragma unroll
        for (int n = 0; n < 4; ++n) acc[m][n] = MFMA(a[m], b[n], acc[m][n]);
    }
  }

  float* outp = (EPI == 3) ? Outf + (size_t)ks * M * N : Outf;
#pragma unroll
  for (int n = 0; n < 4; ++n) {
    int gcol = n0 + wc + n * 16 + lr;
    float bc = (EPI == 3) ? 0.f : bias[gcol];
#pragma unroll
    for (int m = 0; m < MF; ++m) {
      int grow = m0 + wr + m * 16 + (l >> 4) * 4;
#pragma unroll
      for (int r = 0; r < 4; ++r) {
        float v = acc[m][n][r] + bc;
        size_t o = (size_t)(grow + r) * N + gcol;
        if (EPI == 1) {
          Outb[o] = (__bf16)fmaxf(v, 0.f);
        } else if (EPI == 0) {
          outp[o] = v + Res[o];
        } else if (EPI == 2) {
          outp[o] = v + (float)ResB[o];
        } else {
          outp[o] = v;
        }
      }
    }
  }
}

// ---------------------------------------------------------------------------
// 32x32 transpose, f32 in -> bf16 out: out[C x R] = bf16(in[R x C]^T)
// ---------------------------------------------------------------------------
__global__ __launch_bounds__(256) void transpose_f32_bf16(
    const float* __restrict__ in, __bf16* __restrict__ out, int R, int C)
{
  __shared__ float tile[32][33];
  int bx = blockIdx.x * 32, by = blockIdx.y * 32;
  int tx = threadIdx.x & 31, ty = threadIdx.x >> 5;
  for (int i = ty; i < 32; i += 8)
    tile[i][tx] = in[(size_t)(by + i) * C + bx + tx];
  __syncthreads();
  for (int i = ty; i < 32; i += 8)
    out[(size_t)(bx + i) * R + by + tx] = (__bf16)tile[tx][i];
}

// ---------------------------------------------------------------------------
// LayerNorm over D=1024, one block per row. OUTF: f32 out; OUTB: bf16 out.
// ---------------------------------------------------------------------------
template <int OUTF, int OUTB>
__global__ __launch_bounds__(256) void ln_kernel(
    const float* __restrict__ in, const float* __restrict__ gam,
    const float* __restrict__ bet, float* __restrict__ out,
    __bf16* __restrict__ outB)
{
  __shared__ float red[8];
  const int row = blockIdx.x, t = threadIdx.x;
  const float* rp = in + (size_t)row * 1024;
  f32x4 v = ((const f32x4*)rp)[t];
  float s = 0.f, ss = 0.f;
#pragma unroll
  for (int j = 0; j < 4; ++j) {
    s += v[j];
    ss += v[j] * v[j];
  }
#pragma unroll
  for (int o = 1; o < 64; o <<= 1) {
    s += __shfl_xor(s, o, 64);
    ss += __shfl_xor(ss, o, 64);
  }
  int w = t >> 6, l = t & 63;
  if (l == 0) { red[w] = s; red[4 + w] = ss; }
  __syncthreads();
  float S = red[0] + red[1] + red[2] + red[3];
  float SS = red[4] + red[5] + red[6] + red[7];
  float mean = S * (1.f / 1024.f);
  float var = SS * (1.f / 1024.f) - mean * mean;
  float rstd = rsqrtf(var + 1e-5f);
  f32x4 ov;
#pragma unroll
  for (int j = 0; j < 4; ++j) {
    int col = t * 4 + j;
    ov[j] = (v[j] - mean) * rstd * gam[col] + bet[col];
  }
  if (OUTF) ((f32x4*)(out + (size_t)row * 1024))[t] = ov;
  if (OUTB) {
    bf16x4 ob;
#pragma unroll
    for (int j = 0; j < 4; ++j) ob[j] = (__bf16)ov[j];
    *(bf16x4*)&outB[(size_t)row * 1024 + t * 4] = ob;
  }
}

// ---------------------------------------------------------------------------
// Fused final LN: x = P0 + P1 + bias + resB (bf16), out = LN(x)*g + b (f32)
// ---------------------------------------------------------------------------
__global__ __launch_bounds__(256) void ln_fuse2(
    const float* __restrict__ P0, const float* __restrict__ P1,
    const float* __restrict__ bias, const __bf16* __restrict__ resB,
    const float* __restrict__ gam, const float* __restrict__ bet,
    float* __restrict__ out)
{
  __shared__ float red[8];
  const int row = blockIdx.x, t = threadIdx.x;
  const size_t ro = (size_t)row * 1024;
  f32x4 v = ((const f32x4*)(P0 + ro))[t];
  f32x4 v1 = ((const f32x4*)(P1 + ro))[t];
  f32x4 bi = ((const f32x4*)bias)[t];
  bf16x4 rb = ((const bf16x4*)(resB + ro))[t];
  float s = 0.f, ss = 0.f;
#pragma unroll
  for (int j = 0; j < 4; ++j) {
    v[j] = v[j] + v1[j] + bi[j] + (float)rb[j];
    s += v[j];
    ss += v[j] * v[j];
  }
#pragma unroll
  for (int o = 1; o < 64; o <<= 1) {
    s += __shfl_xor(s, o, 64);
    ss += __shfl_xor(ss, o, 64);
  }
  int w = t >> 6, l = t & 63;
  if (l == 0) { red[w] = s; red[4 + w] = ss; }
  __syncthreads();
  float S = red[0] + red[1] + red[2] + red[3];
  float SS = red[4] + red[5] + red[6] + red[7];
  float mean = S * (1.f / 1024.f);
  float var = SS * (1.f / 1024.f) - mean * mean;
  float rstd = rsqrtf(var + 1e-5f);
  f32x4 ov;
#pragma unroll
  for (int j = 0; j < 4; ++j) {
    int col = t * 4 + j;
    ov[j] = (v[j] - mean) * rstd * gam[col] + bet[col];
  }
  ((f32x4*)(out + ro))[t] = ov;
}

// ---------------------------------------------------------------------------
extern "C" void kernel_launch(void* const* d_in, const int* in_sizes, int n_in,
                              void* d_out, int out_size, void* d_ws, size_t ws_size,
                              hipStream_t stream) {
  const float* k_in = (const float*)d_in[0];
  const float* v_in = (const float*)d_in[1];
  const float* q_in = (const float*)d_in[2];
  const float* r_in = (const float*)d_in[3];
  const float* Wf = (const float*)d_in[4];
  const float* bf = (const float*)d_in[5];
  const float* g1 = (const float*)d_in[6];
  const float* b1 = (const float*)d_in[7];
  const float* W1 = (const float*)d_in[8];
  const float* bw1 = (const float*)d_in[9];
  const float* W2 = (const float*)d_in[10];
  const float* bw2 = (const float*)d_in[11];
  const float* g2 = (const float*)d_in[12];
  const float* b2 = (const float*)d_in[13];

  float* out0 = (float*)d_out;          // [4096,1024]
  float* attn = out0 + 4194304;         // [64,1024,1024]

  char* W = (char*)d_ws;
  const size_t MB = 1024 * 1024;
  char* KHimg = W + 0;                   // 8MB
  char* KLimg = W + 8 * MB;              // 8MB
  char* VTimg = W + 16 * MB;             // 8MB
  __bf16* WFT = (__bf16*)(W + 24 * MB);  // 2MB
  __bf16* W1T = (__bf16*)(W + 26 * MB);  // 8MB
  __bf16* W2T = (__bf16*)(W + 34 * MB);  // 8MB
  __bf16* CTX = (__bf16*)(W + 42 * MB);  // 8MB
  __bf16* Xb = (__bf16*)(W + 50 * MB);   // 8MB
  __bf16* Hb = (__bf16*)(W + 58 * MB);   // 32MB
  float* T1 = (float*)(W + 90 * MB);     // 16MB
  float* P0 = (float*)(W + 106 * MB);    // 16MB split-K partial 0 (reuses)
  float* P1 = (float*)(W + 122 * MB);    // 16MB split-K partial 1

  prep_kv<<<2048, 256, 0, stream>>>(k_in, q_in, KHimg, KLimg, VTimg);
  transpose_f32_bf16<<<dim3(32, 32), 256, 0, stream>>>(Wf, WFT, 1024, 1024);
  transpose_f32_bf16<<<dim3(128, 32), 256, 0, stream>>>(W1, W1T, 1024, 4096);
  transpose_f32_bf16<<<dim3(32, 128), 256, 0, stream>>>(W2, W2T, 4096, 1024);

  attn_v6<<<512, 512, 0, stream>>>(v_in, KHimg, KLimg, VTimg, attn, CTX);

  // t1 = r + ctx @ Wf + bf
  gemm_bt<0, 64><<<512, 256, 0, stream>>>(CTX, WFT, bf, r_in, nullptr, T1,
                                          nullptr, 4096, 1024, 1024, 1024, 8, 512);
  // x = LN(t1) -> bf16 only
  ln_kernel<0, 1><<<4096, 256, 0, stream>>>(T1, g1, b1, nullptr, Xb);
  // h = relu(x @ W1 + bw1) -> bf16
  gemm_bt<1, 128><<<1024, 256, 0, stream>>>(Xb, W1T, bw1, nullptr, nullptr,
                                            nullptr, Hb, 4096, 4096, 1024, 1024,
                                            32, 1024);
  // split-K=2 partials of h @ W2  (BM=128, 256 tiles x 2 slices)
  gemm_bt<3, 128><<<512, 256, 0, stream>>>(Hb, W2T, nullptr, nullptr, nullptr,
                                           P0, nullptr, 4096, 1024, 4096, 2048,
                                           8, 256);
  // out = LN(P0 + P1 + bw2 + x)
  ln_fuse2<<<4096, 256, 0, stream>>>(P0, P1, bw2, Xb, g2, b2, out0);
}